// Round 1
// baseline (315.746 us; speedup 1.0000x reference)
//
#include <hip/hip_runtime.h>
#include <hip/hip_bf16.h>
#include <stdint.h>
#include <math.h>

typedef __bf16 bf16_t;
typedef __attribute__((ext_vector_type(8))) __bf16 bf16x8;
typedef __attribute__((ext_vector_type(4))) __bf16 bf16x4;
typedef __attribute__((ext_vector_type(4))) float f32x4;

static constexpr int S = 2048;
static constexpr int DM = 2048;
static constexpr int NH = 16;
static constexpr int NKV = 4;
static constexpr int DH = 128;

#define MFMA16(a, b, c) __builtin_amdgcn_mfma_f32_16x16x32_bf16((a), (b), (c), 0, 0, 0)

__device__ __forceinline__ void gload_lds16(const void* g, void* l) {
  __builtin_amdgcn_global_load_lds((__attribute__((address_space(1))) void*)(g),
                                   (__attribute__((address_space(3))) void*)(l), 16, 0, 0);
}

// ---- RoPE table: [S][64] float2 {sin, cos}; angle = p * base^(-j/64)
__global__ void rope_table_k(float2* __restrict__ tab) {
  int p = blockIdx.x;
  int j = threadIdx.x;
  double inv = exp2(-(double)j * 13.287712379549449 / 64.0);  // log2(10000)
  double ang = (double)p * inv;
  tab[p * 64 + j] = make_float2((float)sin(ang), (float)cos(ang));
}

// ---- f32 -> bf16 flat convert
__global__ void cvt_bf16_k(const float* __restrict__ in, bf16_t* __restrict__ out, int n) {
  int i = (blockIdx.x * blockDim.x + threadIdx.x) * 4;
  if (i >= n) return;
  f32x4 v = *(const f32x4*)(in + i);
  bf16x4 o;
  o[0] = (bf16_t)v[0]; o[1] = (bf16_t)v[1]; o[2] = (bf16_t)v[2]; o[3] = (bf16_t)v[3];
  *(bf16x4*)(out + i) = o;
}

// ---- weight transpose+convert: in[b][r][c] f32 -> out[(b*rb + c)*ldo + b*cb + r] bf16
__global__ void transpose_w_k(const float* __restrict__ in, bf16_t* __restrict__ out,
                              int R, int C, int rb, int cb, int ldo) {
  __shared__ float tile[32][33];
  int b = blockIdx.z;
  int c0 = blockIdx.x * 32, r0 = blockIdx.y * 32;
  int tx = threadIdx.x, ty = threadIdx.y;  // 32 x 8
  const float* src = in + (size_t)b * R * C;
  #pragma unroll
  for (int j = 0; j < 32; j += 8)
    tile[ty + j][tx] = src[(size_t)(r0 + ty + j) * C + c0 + tx];
  __syncthreads();
  #pragma unroll
  for (int j = 0; j < 32; j += 8) {
    int c = c0 + ty + j;
    int r = r0 + tx;
    out[(size_t)(b * rb + c) * ldo + b * cb + r] = (bf16_t)tile[tx][ty + j];
  }
}

// ---- bf16 transpose per batch: in[b][r][c] -> out[b][c][r]
__global__ void transpose_v_k(const bf16_t* __restrict__ in, bf16_t* __restrict__ out,
                              int R, int C) {
  __shared__ bf16_t tile[32][33];
  int b = blockIdx.z;
  int c0 = blockIdx.x * 32, r0 = blockIdx.y * 32;
  int tx = threadIdx.x, ty = threadIdx.y;
  const bf16_t* src = in + (size_t)b * R * C;
  bf16_t* dst = out + (size_t)b * R * C;
  #pragma unroll
  for (int j = 0; j < 32; j += 8)
    tile[ty + j][tx] = src[(size_t)(r0 + ty + j) * C + c0 + tx];
  __syncthreads();
  #pragma unroll
  for (int j = 0; j < 32; j += 8)
    dst[(size_t)(c0 + ty + j) * R + r0 + tx] = tile[tx][ty + j];
}

// ---- NeoX rotary in place on [heads][S][128]; x'[j] = x[j]c - x[j+64]s ; x'[j+64] = x[j+64]c + x[j]s
__global__ void rope_apply_k(bf16_t* __restrict__ x, const float2* __restrict__ tab, float scale) {
  int row = blockIdx.x * 4 + (threadIdx.x >> 6);  // h*S + p
  int j = threadIdx.x & 63;
  int p = row & (S - 1);
  bf16_t* r = x + (size_t)row * DH;
  float a = (float)r[j], b = (float)r[j + 64];
  float2 sc = tab[p * 64 + j];
  r[j] = (bf16_t)((a * sc.y - b * sc.x) * scale);
  r[j + 64] = (bf16_t)((b * sc.y + a * sc.x) * scale);
}

// ---- GEMM: C[M,N] = A[M,K] * BT[N,K]^T + bias[col]
// EPI 0: bf16 out in head-split layout out[(col>>7)*S + row][col&127]
// EPI 1: f32 out row-major [M][N]
template <int EPI>
__global__ __launch_bounds__(256)
void gemm_bt_k(const bf16_t* __restrict__ A, const bf16_t* __restrict__ B,
               const float* __restrict__ bias, void* __restrict__ Cout,
               int M, int N, int K) {
  const int n0 = blockIdx.x * 128, m0 = blockIdx.y * 128;
  const int t = threadIdx.x;
  const int lane = t & 63, w = t >> 6;
  const int l15 = lane & 15, lg = lane >> 4;
  const int wr = (w >> 1) * 64, wc = (w & 1) * 64;

  __shared__ bf16_t lA[128 * 64];  // [row][64], 8 slots of 8, slot ^= row&7
  __shared__ bf16_t lB[128 * 64];

  f32x4 acc[4][4] = {};
  const int srow = t >> 3;
  const int sslot = t & 7;
  (void)M;

  for (int kt = 0; kt < K; kt += 64) {
    __syncthreads();
    #pragma unroll
    for (int i = 0; i < 4; ++i) {
      int row = i * 32 + srow;
      int ss = sslot ^ (row & 7);
      gload_lds16(A + (size_t)(m0 + row) * K + kt + ss * 8, (void*)(lA + i * 2048 + t * 8));
    }
    #pragma unroll
    for (int i = 0; i < 4; ++i) {
      int row = i * 32 + srow;
      int ss = sslot ^ (row & 7);
      gload_lds16(B + (size_t)(n0 + row) * K + kt + ss * 8, (void*)(lB + i * 2048 + t * 8));
    }
    __syncthreads();
    #pragma unroll
    for (int kk = 0; kk < 2; ++kk) {
      bf16x8 af[4], bfv[4];
      #pragma unroll
      for (int f = 0; f < 4; ++f) {
        int row = wr + f * 16 + l15;
        int slot = kk * 4 + lg;
        af[f] = *(const bf16x8*)(lA + row * 64 + ((slot ^ (row & 7)) * 8));
      }
      #pragma unroll
      for (int f = 0; f < 4; ++f) {
        int row = wc + f * 16 + l15;
        int slot = kk * 4 + lg;
        bfv[f] = *(const bf16x8*)(lB + row * 64 + ((slot ^ (row & 7)) * 8));
      }
      #pragma unroll
      for (int fm = 0; fm < 4; ++fm)
        #pragma unroll
        for (int fn = 0; fn < 4; ++fn)
          acc[fm][fn] = MFMA16(af[fm], bfv[fn], acc[fm][fn]);
    }
  }

  #pragma unroll
  for (int fm = 0; fm < 4; ++fm) {
    int rowb = m0 + wr + fm * 16 + lg * 4;
    #pragma unroll
    for (int fn = 0; fn < 4; ++fn) {
      int col = n0 + wc + fn * 16 + l15;
      float bb = bias[col];
      #pragma unroll
      for (int r = 0; r < 4; ++r) {
        float v = acc[fm][fn][r] + bb;
        int rr = rowb + r;
        if (EPI == 0) {
          ((bf16_t*)Cout)[((size_t)(col >> 7) * S + rr) * DH + (col & 127)] = (bf16_t)v;
        } else {
          ((float*)Cout)[(size_t)rr * N + col] = v;
        }
      }
    }
  }
}

// ---- flash attention: Q[16][S][128] (rope'd, pre-scaled by log2e/sqrt(128)),
// K[4][S][128] (rope'd), Vt[4][128][S], out Z[S][2048] with cols h*128+d.
__global__ __launch_bounds__(256)
void attn_k(const bf16_t* __restrict__ Q, const bf16_t* __restrict__ K,
            const bf16_t* __restrict__ Vt, bf16_t* __restrict__ Z) {
  const int h = blockIdx.y;
  const int qblk = (int)(gridDim.x - 1 - blockIdx.x);  // heavy blocks first
  const int q0 = qblk * 64;
  const int hkv = h >> 2;
  const int t = threadIdx.x;
  const int lane = t & 63, w = t >> 6;
  const int l15 = lane & 15, lg = lane >> 4;

  __shared__ bf16_t lK[64 * 128];    // [key][d], 16 slots, slot ^= row&15
  __shared__ bf16_t lV[128 * 64];    // [d][key], 8 slots, slot ^= row&7
  __shared__ bf16_t lP[4][16 * 64];  // per-wave P[q][key], 8 slots, slot ^= q&7

  const int qrow = q0 + w * 16 + l15;  // this lane's softmax row
  bf16x8 qf[4];
  #pragma unroll
  for (int kk = 0; kk < 4; ++kk)
    qf[kk] = *(const bf16x8*)(Q + ((size_t)h * S + qrow) * DH + kk * 32 + lg * 8);

  f32x4 oacc[8] = {};
  float m_run = -1e30f, l_run = 0.f;

  const int ktmax = q0 >> 6;
  for (int kt = 0; kt <= ktmax; ++kt) {
    __syncthreads();
    #pragma unroll
    for (int i = 0; i < 4; ++i) {
      int row = i * 16 + (t >> 4);
      int ss = (t & 15) ^ (row & 15);
      gload_lds16(K + ((size_t)hkv * S + kt * 64 + row) * DH + ss * 8,
                  (void*)(lK + i * 2048 + t * 8));
    }
    #pragma unroll
    for (int i = 0; i < 4; ++i) {
      int row = i * 32 + (t >> 3);
      int ss = (t & 7) ^ (row & 7);
      gload_lds16(Vt + ((size_t)hkv * DH + row) * S + kt * 64 + ss * 8,
                  (void*)(lV + i * 2048 + t * 8));
    }
    __syncthreads();

    // S^T tile = K_tile (64x128) * Q^T : lane holds q=l15, keys fm*16+lg*4+r
    f32x4 sacc[4] = {};
    #pragma unroll
    for (int kk = 0; kk < 4; ++kk) {
      #pragma unroll
      for (int fm = 0; fm < 4; ++fm) {
        int row = fm * 16 + l15;
        int slot = kk * 4 + lg;
        bf16x8 kf = *(const bf16x8*)(lK + row * 128 + ((slot ^ (row & 15)) * 8));
        sacc[fm] = MFMA16(kf, qf[kk], sacc[fm]);
      }
    }

    const bool diag = (kt == ktmax);
    float smax = -1e30f;
    #pragma unroll
    for (int fm = 0; fm < 4; ++fm) {
      #pragma unroll
      for (int r = 0; r < 4; ++r) {
        float s = sacc[fm][r];
        if (diag) {
          int keyg = kt * 64 + fm * 16 + lg * 4 + r;
          if (keyg > qrow) s = -1e30f;
        }
        sacc[fm][r] = s;
        smax = fmaxf(smax, s);
      }
    }
    smax = fmaxf(smax, __shfl_xor(smax, 16));
    smax = fmaxf(smax, __shfl_xor(smax, 32));
    float m_new = fmaxf(m_run, smax);
    float alpha = exp2f(m_run - m_new);
    float psum = 0.f;
    #pragma unroll
    for (int fm = 0; fm < 4; ++fm) {
      bf16x4 pk;
      #pragma unroll
      for (int r = 0; r < 4; ++r) {
        float p = exp2f(sacc[fm][r] - m_new);
        psum += p;
        pk[r] = (bf16_t)p;
      }
      int slot = fm * 2 + (lg >> 1);
      char* dst = (char*)(&lP[w][0]) + l15 * 128 + ((slot ^ (l15 & 7)) * 16) + ((lg & 1) * 8);
      *(bf16x4*)dst = pk;
    }
    psum += __shfl_xor(psum, 16);
    psum += __shfl_xor(psum, 32);
    l_run = l_run * alpha + psum;
    m_run = m_new;

    // rescale O (rows lg*4+r need alpha of q-lane lg*4+r)
    #pragma unroll
    for (int r = 0; r < 4; ++r) {
      float ar = __shfl(alpha, lg * 4 + r);
      #pragma unroll
      for (int n = 0; n < 8; ++n) oacc[n][r] *= ar;
    }

    // O += P (16x64) * V (64x128)
    #pragma unroll
    for (int kk2 = 0; kk2 < 2; ++kk2) {
      int pslot = kk2 * 4 + lg;
      bf16x8 pf = *(const bf16x8*)((char*)(&lP[w][0]) + l15 * 128 + ((pslot ^ (l15 & 7)) * 16));
      #pragma unroll
      for (int n = 0; n < 8; ++n) {
        int vrow = n * 16 + l15;
        int vslot = kk2 * 4 + lg;
        bf16x8 vf = *(const bf16x8*)(lV + vrow * 64 + ((vslot ^ (vrow & 7)) * 8));
        oacc[n] = MFMA16(pf, vf, oacc[n]);
      }
    }
  }

  #pragma unroll
  for (int r = 0; r < 4; ++r) {
    float lr = __shfl(l_run, lg * 4 + r);
    float inv = 1.0f / lr;
    int qg = q0 + w * 16 + lg * 4 + r;
    #pragma unroll
    for (int n = 0; n < 8; ++n) {
      int d = n * 16 + l15;
      Z[(size_t)qg * DM + h * DH + d] = (bf16_t)(oacc[n][r] * inv);
    }
  }
}

extern "C" void kernel_launch(void* const* d_in, const int* in_sizes, int n_in,
                              void* d_out, int out_size, void* d_ws, size_t ws_size,
                              hipStream_t stream) {
  (void)in_sizes; (void)n_in; (void)out_size; (void)ws_size;
  const float* Xq = (const float*)d_in[0];
  const float* Xk = (const float*)d_in[1];
  const float* Xv = (const float*)d_in[2];
  const float* WQ = (const float*)d_in[3];
  const float* bQ = (const float*)d_in[4];
  const float* WK = (const float*)d_in[5];
  const float* bK = (const float*)d_in[6];
  const float* WV = (const float*)d_in[7];
  const float* bV = (const float*)d_in[8];
  const float* WO = (const float*)d_in[9];
  const float* bO = (const float*)d_in[10];

  char* w = (char*)d_ws;
  float2* tab = (float2*)w;  // 2048*64*8 = 1 MiB
  bf16_t* xq  = (bf16_t*)(w + (1 << 20));
  bf16_t* xk  = xq + 4194304;
  bf16_t* xv  = xk + 4194304;
  bf16_t* wqT = xv + 4194304;   // [2048][2048]: row h*128+k, col d
  bf16_t* wkT = wqT + 4194304;  // [512][2048]
  bf16_t* wvT = wkT + 1048576;  // [512][2048]
  bf16_t* woT = wvT + 1048576;  // [2048][2048]: row m, col h*128+d
  bf16_t* Qb  = woT + 4194304;  // [16][2048][128]
  bf16_t* Kb  = Qb + 4194304;   // [4][2048][128]
  bf16_t* Vb  = Kb + 1048576;   // [4][2048][128]
  bf16_t* Vtb = Vb + 1048576;   // [4][128][2048]
  bf16_t* Zb  = Vtb + 1048576;  // [2048][2048]

  rope_table_k<<<dim3(S), dim3(64), 0, stream>>>(tab);
  cvt_bf16_k<<<dim3(4096), dim3(256), 0, stream>>>(Xq, xq, 4194304);
  cvt_bf16_k<<<dim3(4096), dim3(256), 0, stream>>>(Xk, xk, 4194304);
  cvt_bf16_k<<<dim3(4096), dim3(256), 0, stream>>>(Xv, xv, 4194304);
  // W_Q (16,2048,128): out[(h*128+k)*2048 + d]
  transpose_w_k<<<dim3(4, 64, 16), dim3(32, 8), 0, stream>>>(WQ, wqT, 2048, 128, 128, 0, 2048);
  transpose_w_k<<<dim3(4, 64, 4), dim3(32, 8), 0, stream>>>(WK, wkT, 2048, 128, 128, 0, 2048);
  transpose_w_k<<<dim3(4, 64, 4), dim3(32, 8), 0, stream>>>(WV, wvT, 2048, 128, 128, 0, 2048);
  // W_O (16,128,2048): out[m*2048 + h*128 + d]
  transpose_w_k<<<dim3(64, 4, 16), dim3(32, 8), 0, stream>>>(WO, woT, 128, 2048, 0, 128, 2048);

  gemm_bt_k<0><<<dim3(16, 16), dim3(256), 0, stream>>>(xq, wqT, bQ, (void*)Qb, 2048, 2048, 2048);
  gemm_bt_k<0><<<dim3(4, 16), dim3(256), 0, stream>>>(xk, wkT, bK, (void*)Kb, 2048, 512, 2048);
  gemm_bt_k<0><<<dim3(4, 16), dim3(256), 0, stream>>>(xv, wvT, bV, (void*)Vb, 2048, 512, 2048);

  transpose_v_k<<<dim3(4, 64, 4), dim3(32, 8), 0, stream>>>(Vb, Vtb, 2048, 128);

  const float qscale = 1.4426950408889634f / sqrtf(128.0f);  // log2e / sqrt(D_HEAD)
  rope_apply_k<<<dim3(NH * S / 4), dim3(256), 0, stream>>>(Qb, tab, qscale);
  rope_apply_k<<<dim3(NKV * S / 4), dim3(256), 0, stream>>>(Kb, tab, 1.0f);

  attn_k<<<dim3(S / 64, NH), dim3(256), 0, stream>>>(Qb, Kb, Vtb, Zb);

  gemm_bt_k<1><<<dim3(16, 16), dim3(256), 0, stream>>>(Zb, woT, bO, d_out, 2048, 2048, 2048);
}

// Round 2
// 254.202 us; speedup vs baseline: 1.2421x; 1.2421x over previous
//
#include <hip/hip_runtime.h>
#include <hip/hip_bf16.h>
#include <stdint.h>
#include <math.h>

typedef __bf16 bf16_t;
typedef __attribute__((ext_vector_type(8))) __bf16 bf16x8;
typedef __attribute__((ext_vector_type(4))) __bf16 bf16x4;
typedef __attribute__((ext_vector_type(4))) float f32x4;

static constexpr int S = 2048;
static constexpr int DM = 2048;
static constexpr int NH = 16;
static constexpr int NKV = 4;
static constexpr int DH = 128;

#define MFMA16(a, b, c) __builtin_amdgcn_mfma_f32_16x16x32_bf16((a), (b), (c), 0, 0, 0)

__device__ __forceinline__ void gload_lds16(const void* g, void* l) {
  __builtin_amdgcn_global_load_lds((__attribute__((address_space(1))) void*)(g),
                                   (__attribute__((address_space(3))) void*)(l), 16, 0, 0);
}

template <int N>
__device__ __forceinline__ void wait_vmcnt() {
  asm volatile("s_waitcnt vmcnt(%0)" :: "n"(N) : "memory");
}
__device__ __forceinline__ void wait_lgkm0() {
  asm volatile("s_waitcnt lgkmcnt(0)" ::: "memory");
}

// ---- RoPE table: [S][64] float2 {sin, cos}; angle = p * base^(-j/64)
__global__ void rope_table_k(float2* __restrict__ tab) {
  int p = blockIdx.x;
  int j = threadIdx.x;
  double inv = exp2(-(double)j * 13.287712379549449 / 64.0);  // log2(10000)
  double ang = (double)p * inv;
  tab[p * 64 + j] = make_float2((float)sin(ang), (float)cos(ang));
}

// ---- f32 -> bf16 flat convert
__global__ void cvt_bf16_k(const float* __restrict__ in, bf16_t* __restrict__ out, int n) {
  int i = (blockIdx.x * blockDim.x + threadIdx.x) * 4;
  if (i >= n) return;
  f32x4 v = *(const f32x4*)(in + i);
  bf16x4 o;
  o[0] = (bf16_t)v[0]; o[1] = (bf16_t)v[1]; o[2] = (bf16_t)v[2]; o[3] = (bf16_t)v[3];
  *(bf16x4*)(out + i) = o;
}

// ---- weight transpose+convert: in[b][r][c] f32 -> out[(b*rb + c)*ldo + b*cb + r] bf16
__global__ void transpose_w_k(const float* __restrict__ in, bf16_t* __restrict__ out,
                              int R, int C, int rb, int cb, int ldo) {
  __shared__ float tile[32][33];
  int b = blockIdx.z;
  int c0 = blockIdx.x * 32, r0 = blockIdx.y * 32;
  int tx = threadIdx.x, ty = threadIdx.y;  // 32 x 8
  const float* src = in + (size_t)b * R * C;
  #pragma unroll
  for (int j = 0; j < 32; j += 8)
    tile[ty + j][tx] = src[(size_t)(r0 + ty + j) * C + c0 + tx];
  __syncthreads();
  #pragma unroll
  for (int j = 0; j < 32; j += 8) {
    int c = c0 + ty + j;
    int r = r0 + tx;
    out[(size_t)(b * rb + c) * ldo + b * cb + r] = (bf16_t)tile[tx][ty + j];
  }
}

// ---- bf16 transpose per batch: in[b][r][c] -> out[b][c][r]
__global__ void transpose_v_k(const bf16_t* __restrict__ in, bf16_t* __restrict__ out,
                              int R, int C) {
  __shared__ bf16_t tile[32][33];
  int b = blockIdx.z;
  int c0 = blockIdx.x * 32, r0 = blockIdx.y * 32;
  int tx = threadIdx.x, ty = threadIdx.y;
  const bf16_t* src = in + (size_t)b * R * C;
  bf16_t* dst = out + (size_t)b * R * C;
  #pragma unroll
  for (int j = 0; j < 32; j += 8)
    tile[ty + j][tx] = src[(size_t)(r0 + ty + j) * C + c0 + tx];
  __syncthreads();
  #pragma unroll
  for (int j = 0; j < 32; j += 8)
    dst[(size_t)(c0 + ty + j) * R + r0 + tx] = tile[tx][ty + j];
}

// ---- NeoX rotary in place on [heads][S][128]
__global__ void rope_apply_k(bf16_t* __restrict__ x, const float2* __restrict__ tab, float scale) {
  int row = blockIdx.x * 4 + (threadIdx.x >> 6);  // h*S + p
  int j = threadIdx.x & 63;
  int p = row & (S - 1);
  bf16_t* r = x + (size_t)row * DH;
  float a = (float)r[j], b = (float)r[j + 64];
  float2 sc = tab[p * 64 + j];
  r[j] = (bf16_t)((a * sc.y - b * sc.x) * scale);
  r[j + 64] = (bf16_t)((b * sc.y + a * sc.x) * scale);
}

// ---- GEMM: C[M,N] = A[M,K] * BT[N,K]^T + bias[col]
// Double-buffered LDS, counted vmcnt (T3/T4 minimal 2-phase).
// EPI 0: bf16 out head-split out[(col>>7)*S + row][col&127]; EPI 1: f32 [M][N]
template <int EPI>
__global__ __launch_bounds__(256)
void gemm_bt_k(const bf16_t* __restrict__ A, const bf16_t* __restrict__ B,
               const float* __restrict__ bias, void* __restrict__ Cout,
               int M, int N, int K) {
  const int n0 = blockIdx.x * 128, m0 = blockIdx.y * 128;
  const int t = threadIdx.x;
  const int lane = t & 63, w = t >> 6;
  const int l15 = lane & 15, lg = lane >> 4;
  const int wr = (w >> 1) * 64, wc = (w & 1) * 64;

  __shared__ bf16_t lA[2][128 * 64];  // [row][64], 8 slots of 8, slot ^= row&7
  __shared__ bf16_t lB[2][128 * 64];

  f32x4 acc[4][4] = {};
  const int srow = t >> 3;
  const int sslot = t & 7;
  (void)M;

  auto stage = [&](int buf, int kt) {
    #pragma unroll
    for (int i = 0; i < 4; ++i) {
      int row = i * 32 + srow;
      int ss = sslot ^ (row & 7);
      gload_lds16(A + (size_t)(m0 + row) * K + kt * 64 + ss * 8,
                  (void*)(&lA[buf][0] + i * 2048 + t * 8));
    }
    #pragma unroll
    for (int i = 0; i < 4; ++i) {
      int row = i * 32 + srow;
      int ss = sslot ^ (row & 7);
      gload_lds16(B + (size_t)(n0 + row) * K + kt * 64 + ss * 8,
                  (void*)(&lB[buf][0] + i * 2048 + t * 8));
    }
  };

  const int nk = K >> 6;
  stage(0, 0);
  for (int kt = 0; kt < nk; ++kt) {
    const int cur = kt & 1;
    if (kt + 1 < nk) {
      stage(cur ^ 1, kt + 1);
      wait_vmcnt<8>();
    } else {
      wait_vmcnt<0>();
    }
    __builtin_amdgcn_s_barrier();
    #pragma unroll
    for (int kk = 0; kk < 2; ++kk) {
      bf16x8 af[4], bfv[4];
      #pragma unroll
      for (int f = 0; f < 4; ++f) {
        int row = wr + f * 16 + l15;
        int slot = kk * 4 + lg;
        af[f] = *(const bf16x8*)(&lA[cur][0] + row * 64 + ((slot ^ (row & 7)) * 8));
      }
      #pragma unroll
      for (int f = 0; f < 4; ++f) {
        int row = wc + f * 16 + l15;
        int slot = kk * 4 + lg;
        bfv[f] = *(const bf16x8*)(&lB[cur][0] + row * 64 + ((slot ^ (row & 7)) * 8));
      }
      #pragma unroll
      for (int fm = 0; fm < 4; ++fm)
        #pragma unroll
        for (int fn = 0; fn < 4; ++fn)
          acc[fm][fn] = MFMA16(af[fm], bfv[fn], acc[fm][fn]);
    }
    wait_lgkm0();
    __builtin_amdgcn_s_barrier();
  }

  #pragma unroll
  for (int fm = 0; fm < 4; ++fm) {
    int rowb = m0 + wr + fm * 16 + lg * 4;
    #pragma unroll
    for (int fn = 0; fn < 4; ++fn) {
      int col = n0 + wc + fn * 16 + l15;
      float bb = bias[col];
      #pragma unroll
      for (int r = 0; r < 4; ++r) {
        float v = acc[fm][fn][r] + bb;
        int rr = rowb + r;
        if (EPI == 0) {
          ((bf16_t*)Cout)[((size_t)(col >> 7) * S + rr) * DH + (col & 127)] = (bf16_t)v;
        } else {
          ((float*)Cout)[(size_t)rr * N + col] = v;
        }
      }
    }
  }
}

// ---- flash attention, double-buffered K/V, counted vmcnt, balanced 1D grid.
// Q[16][S][128] (rope'd, pre-scaled by log2e/sqrt(128)), K[4][S][128] (rope'd),
// Vt[4][128][S], out Z[S][2048] cols h*128+d.
__global__ __launch_bounds__(256)
void attn_k(const bf16_t* __restrict__ Q, const bf16_t* __restrict__ K,
            const bf16_t* __restrict__ Vt, bf16_t* __restrict__ Z) {
  const int lin = blockIdx.x;         // 0..511
  const int h = lin & 15;
  const int ip = lin >> 4;            // 0..31
  const int qblk = (ip < 16) ? ip : 47 - ip;  // pair lin, lin+256 -> weights sum 33
  const int q0 = qblk * 64;
  const int hkv = h >> 2;
  const int t = threadIdx.x;
  const int lane = t & 63, w = t >> 6;
  const int l15 = lane & 15, lg = lane >> 4;

  __shared__ bf16_t lK[2][64 * 128];    // [key][d], 16 slots, slot ^= row&15
  __shared__ bf16_t lV[2][128 * 64];    // [d][key], 8 slots, slot ^= row&7
  __shared__ bf16_t lP[4][16 * 64];     // per-wave P[q][key], 8 slots, slot ^= q&7

  const int qrow = q0 + w * 16 + l15;   // this lane's softmax row
  bf16x8 qf[4];
  #pragma unroll
  for (int kk = 0; kk < 4; ++kk)
    qf[kk] = *(const bf16x8*)(Q + ((size_t)h * S + qrow) * DH + kk * 32 + lg * 8);

  auto stageKV = [&](int buf, int kt) {
    #pragma unroll
    for (int i = 0; i < 4; ++i) {
      int row = i * 16 + (t >> 4);
      int ss = (t & 15) ^ (row & 15);
      gload_lds16(K + ((size_t)hkv * S + kt * 64 + row) * DH + ss * 8,
                  (void*)(&lK[buf][0] + i * 2048 + t * 8));
    }
    #pragma unroll
    for (int i = 0; i < 4; ++i) {
      int row = i * 32 + (t >> 3);
      int ss = (t & 7) ^ (row & 7);
      gload_lds16(Vt + ((size_t)hkv * DH + row) * S + kt * 64 + ss * 8,
                  (void*)(&lV[buf][0] + i * 2048 + t * 8));
    }
  };

  f32x4 oacc[8] = {};
  float m_run = -1e30f, l_run = 0.f;

  const int ktmax = q0 >> 6;
  stageKV(0, 0);
  for (int kt = 0; kt <= ktmax; ++kt) {
    const int cur = kt & 1;
    if (kt < ktmax) {
      stageKV(cur ^ 1, kt + 1);
      wait_vmcnt<8>();
    } else {
      wait_vmcnt<0>();
    }
    __builtin_amdgcn_s_barrier();

    // S^T tile = K_tile (64x128) * Q^T : lane holds q=l15, keys fm*16+lg*4+r
    f32x4 sacc[4] = {};
    #pragma unroll
    for (int kk = 0; kk < 4; ++kk) {
      #pragma unroll
      for (int fm = 0; fm < 4; ++fm) {
        int row = fm * 16 + l15;
        int slot = kk * 4 + lg;
        bf16x8 kf = *(const bf16x8*)(&lK[cur][0] + row * 128 + ((slot ^ (row & 15)) * 8));
        sacc[fm] = MFMA16(kf, qf[kk], sacc[fm]);
      }
    }

    const bool diag = (kt == ktmax);
    float smax = -1e30f;
    #pragma unroll
    for (int fm = 0; fm < 4; ++fm) {
      #pragma unroll
      for (int r = 0; r < 4; ++r) {
        float s = sacc[fm][r];
        if (diag) {
          int keyg = kt * 64 + fm * 16 + lg * 4 + r;
          if (keyg > qrow) s = -1e30f;
        }
        sacc[fm][r] = s;
        smax = fmaxf(smax, s);
      }
    }
    smax = fmaxf(smax, __shfl_xor(smax, 16));
    smax = fmaxf(smax, __shfl_xor(smax, 32));
    float m_new = fmaxf(m_run, smax);
    float alpha = exp2f(m_run - m_new);
    float psum = 0.f;
    #pragma unroll
    for (int fm = 0; fm < 4; ++fm) {
      bf16x4 pk;
      #pragma unroll
      for (int r = 0; r < 4; ++r) {
        float p = exp2f(sacc[fm][r] - m_new);
        psum += p;
        pk[r] = (bf16_t)p;
      }
      int slot = fm * 2 + (lg >> 1);
      char* dst = (char*)(&lP[w][0]) + l15 * 128 + ((slot ^ (l15 & 7)) * 16) + ((lg & 1) * 8);
      *(bf16x4*)dst = pk;
    }
    psum += __shfl_xor(psum, 16);
    psum += __shfl_xor(psum, 32);
    l_run = l_run * alpha + psum;
    m_run = m_new;

    // rescale O (rows lg*4+r need alpha of q-lane lg*4+r)
    #pragma unroll
    for (int r = 0; r < 4; ++r) {
      float ar = __shfl(alpha, lg * 4 + r);
      #pragma unroll
      for (int n = 0; n < 8; ++n) oacc[n][r] *= ar;
    }

    // O += P (16x64) * V (64x128)
    #pragma unroll
    for (int kk2 = 0; kk2 < 2; ++kk2) {
      int pslot = kk2 * 4 + lg;
      bf16x8 pf = *(const bf16x8*)((char*)(&lP[w][0]) + l15 * 128 + ((pslot ^ (l15 & 7)) * 16));
      #pragma unroll
      for (int n = 0; n < 8; ++n) {
        int vrow = n * 16 + l15;
        int vslot = kk2 * 4 + lg;
        bf16x8 vf = *(const bf16x8*)(&lV[cur][0] + vrow * 64 + ((vslot ^ (vrow & 7)) * 8));
        oacc[n] = MFMA16(pf, vf, oacc[n]);
      }
    }
    wait_lgkm0();
    __builtin_amdgcn_s_barrier();
  }

  #pragma unroll
  for (int r = 0; r < 4; ++r) {
    float lr = __shfl(l_run, lg * 4 + r);
    float inv = 1.0f / lr;
    int qg = q0 + w * 16 + lg * 4 + r;
    #pragma unroll
    for (int n = 0; n < 8; ++n) {
      int d = n * 16 + l15;
      Z[(size_t)qg * DM + h * DH + d] = (bf16_t)(oacc[n][r] * inv);
    }
  }
}

extern "C" void kernel_launch(void* const* d_in, const int* in_sizes, int n_in,
                              void* d_out, int out_size, void* d_ws, size_t ws_size,
                              hipStream_t stream) {
  (void)in_sizes; (void)n_in; (void)out_size; (void)ws_size;
  const float* Xq = (const float*)d_in[0];
  const float* Xk = (const float*)d_in[1];
  const float* Xv = (const float*)d_in[2];
  const float* WQ = (const float*)d_in[3];
  const float* bQ = (const float*)d_in[4];
  const float* WK = (const float*)d_in[5];
  const float* bK = (const float*)d_in[6];
  const float* WV = (const float*)d_in[7];
  const float* bV = (const float*)d_in[8];
  const float* WO = (const float*)d_in[9];
  const float* bO = (const float*)d_in[10];

  char* w = (char*)d_ws;
  float2* tab = (float2*)w;  // 2048*64*8 = 1 MiB
  bf16_t* xq  = (bf16_t*)(w + (1 << 20));
  bf16_t* xk  = xq + 4194304;
  bf16_t* xv  = xk + 4194304;
  bf16_t* wqT = xv + 4194304;   // [2048][2048]: row h*128+k, col d
  bf16_t* wkT = wqT + 4194304;  // [512][2048]
  bf16_t* wvT = wkT + 1048576;  // [512][2048]
  bf16_t* woT = wvT + 1048576;  // [2048][2048]: row m, col h*128+d
  bf16_t* Qb  = woT + 4194304;  // [16][2048][128]
  bf16_t* Kb  = Qb + 4194304;   // [4][2048][128]
  bf16_t* Vb  = Kb + 1048576;   // [4][2048][128]
  bf16_t* Vtb = Vb + 1048576;   // [4][128][2048]
  bf16_t* Zb  = Vtb + 1048576;  // [2048][2048]

  rope_table_k<<<dim3(S), dim3(64), 0, stream>>>(tab);
  cvt_bf16_k<<<dim3(4096), dim3(256), 0, stream>>>(Xq, xq, 4194304);
  cvt_bf16_k<<<dim3(4096), dim3(256), 0, stream>>>(Xk, xk, 4194304);
  cvt_bf16_k<<<dim3(4096), dim3(256), 0, stream>>>(Xv, xv, 4194304);
  // W_Q (16,2048,128): out[(h*128+k)*2048 + d]
  transpose_w_k<<<dim3(4, 64, 16), dim3(32, 8), 0, stream>>>(WQ, wqT, 2048, 128, 128, 0, 2048);
  transpose_w_k<<<dim3(4, 64, 4), dim3(32, 8), 0, stream>>>(WK, wkT, 2048, 128, 128, 0, 2048);
  transpose_w_k<<<dim3(4, 64, 4), dim3(32, 8), 0, stream>>>(WV, wvT, 2048, 128, 128, 0, 2048);
  // W_O (16,128,2048): out[m*2048 + h*128 + d]
  transpose_w_k<<<dim3(64, 4, 16), dim3(32, 8), 0, stream>>>(WO, woT, 128, 2048, 0, 128, 2048);

  gemm_bt_k<0><<<dim3(16, 16), dim3(256), 0, stream>>>(xq, wqT, bQ, (void*)Qb, 2048, 2048, 2048);
  gemm_bt_k<0><<<dim3(4, 16), dim3(256), 0, stream>>>(xk, wkT, bK, (void*)Kb, 2048, 512, 2048);
  gemm_bt_k<0><<<dim3(4, 16), dim3(256), 0, stream>>>(xv, wvT, bV, (void*)Vb, 2048, 512, 2048);

  transpose_v_k<<<dim3(4, 64, 4), dim3(32, 8), 0, stream>>>(Vb, Vtb, 2048, 128);

  const float qscale = 1.4426950408889634f / sqrtf(128.0f);  // log2e / sqrt(D_HEAD)
  rope_apply_k<<<dim3(NH * S / 4), dim3(256), 0, stream>>>(Qb, tab, qscale);
  rope_apply_k<<<dim3(NKV * S / 4), dim3(256), 0, stream>>>(Kb, tab, 1.0f);

  attn_k<<<dim3(512), dim3(256), 0, stream>>>(Qb, Kb, Vtb, Zb);

  gemm_bt_k<1><<<dim3(16, 16), dim3(256), 0, stream>>>(Zb, woT, bO, d_out, 2048, 2048, 2048);
}

// Round 3
// 170.242 us; speedup vs baseline: 1.8547x; 1.4932x over previous
//
#include <hip/hip_runtime.h>
#include <hip/hip_bf16.h>
#include <stdint.h>
#include <math.h>

typedef __bf16 bf16_t;
typedef __attribute__((ext_vector_type(8))) __bf16 bf16x8;
typedef __attribute__((ext_vector_type(4))) __bf16 bf16x4;
typedef __attribute__((ext_vector_type(4))) float f32x4;

static constexpr int S = 2048;
static constexpr int DM = 2048;
static constexpr int NH = 16;
static constexpr int NKV = 4;
static constexpr int DH = 128;

#define MFMA16(a, b, c) __builtin_amdgcn_mfma_f32_16x16x32_bf16((a), (b), (c), 0, 0, 0)

__device__ __forceinline__ void gload_lds16(const void* g, void* l) {
  __builtin_amdgcn_global_load_lds((__attribute__((address_space(1))) void*)(g),
                                   (__attribute__((address_space(3))) void*)(l), 16, 0, 0);
}

template <int N>
__device__ __forceinline__ void wait_vmcnt() {
  asm volatile("s_waitcnt vmcnt(%0)" :: "n"(N) : "memory");
}
__device__ __forceinline__ void wait_lgkm0() {
  asm volatile("s_waitcnt lgkmcnt(0)" ::: "memory");
}

// ---- RoPE table: [S][64] float2 {sin, cos}; angle = p * base^(-j/64)
__global__ void rope_table_k(float2* __restrict__ tab) {
  int p = blockIdx.x;
  int j = threadIdx.x;
  double inv = exp2(-(double)j * 13.287712379549449 / 64.0);  // log2(10000)
  double ang = (double)p * inv;
  tab[p * 64 + j] = make_float2((float)sin(ang), (float)cos(ang));
}

// ---- fused f32 -> bf16 convert of Xq, Xk, Xv
__global__ void cvt3_k(const float* __restrict__ Xq, const float* __restrict__ Xk,
                       const float* __restrict__ Xv, bf16_t* __restrict__ xq,
                       bf16_t* __restrict__ xk, bf16_t* __restrict__ xv) {
  int i = (blockIdx.x * 256 + threadIdx.x) * 4;
  const float* in; bf16_t* out; int off;
  if (i < 4194304) { in = Xq; out = xq; off = i; }
  else if (i < 8388608) { in = Xk; out = xk; off = i - 4194304; }
  else { in = Xv; out = xv; off = i - 8388608; }
  f32x4 v = *(const f32x4*)(in + off);
  bf16x4 o;
  o[0] = (bf16_t)v[0]; o[1] = (bf16_t)v[1]; o[2] = (bf16_t)v[2]; o[3] = (bf16_t)v[3];
  *(bf16x4*)(out + off) = o;
}

// ---- weight transpose+convert: in[b][r][c] f32 -> out[(b*rb + c)*ldo + b*cb + r] bf16
__global__ void transpose_w_k(const float* __restrict__ in, bf16_t* __restrict__ out,
                              int R, int C, int rb, int cb, int ldo) {
  __shared__ float tile[32][33];
  int b = blockIdx.z;
  int c0 = blockIdx.x * 32, r0 = blockIdx.y * 32;
  int tx = threadIdx.x, ty = threadIdx.y;  // 32 x 8
  const float* src = in + (size_t)b * R * C;
  #pragma unroll
  for (int j = 0; j < 32; j += 8)
    tile[ty + j][tx] = src[(size_t)(r0 + ty + j) * C + c0 + tx];
  __syncthreads();
  #pragma unroll
  for (int j = 0; j < 32; j += 8) {
    int c = c0 + ty + j;
    int r = r0 + tx;
    out[(size_t)(b * rb + c) * ldo + b * cb + r] = (bf16_t)tile[tx][ty + j];
  }
}

// ---- fused WK+WV transpose: z in [0,8), b=z&3, sel=z>>2
__global__ void transpose_wkv_k(const float* __restrict__ WK, const float* __restrict__ WV,
                                bf16_t* __restrict__ wkT, bf16_t* __restrict__ wvT) {
  __shared__ float tile[32][33];
  int z = blockIdx.z;
  int b = z & 3;
  const float* in = (z < 4) ? WK : WV;
  bf16_t* out = (z < 4) ? wkT : wvT;
  int c0 = blockIdx.x * 32, r0 = blockIdx.y * 32;
  int tx = threadIdx.x, ty = threadIdx.y;
  const float* src = in + (size_t)b * 2048 * 128;
  #pragma unroll
  for (int j = 0; j < 32; j += 8)
    tile[ty + j][tx] = src[(size_t)(r0 + ty + j) * 128 + c0 + tx];
  __syncthreads();
  #pragma unroll
  for (int j = 0; j < 32; j += 8) {
    int c = c0 + ty + j;
    int r = r0 + tx;
    out[(size_t)(b * 128 + c) * 2048 + r] = (bf16_t)tile[tx][ty + j];
  }
}

// ---- bf16 transpose per batch: in[b][r][c] -> out[b][c][r]
__global__ void transpose_v_k(const bf16_t* __restrict__ in, bf16_t* __restrict__ out,
                              int R, int C) {
  __shared__ bf16_t tile[32][33];
  int b = blockIdx.z;
  int c0 = blockIdx.x * 32, r0 = blockIdx.y * 32;
  int tx = threadIdx.x, ty = threadIdx.y;
  const bf16_t* src = in + (size_t)b * R * C;
  bf16_t* dst = out + (size_t)b * R * C;
  #pragma unroll
  for (int j = 0; j < 32; j += 8)
    tile[ty + j][tx] = src[(size_t)(r0 + ty + j) * C + c0 + tx];
  __syncthreads();
  #pragma unroll
  for (int j = 0; j < 32; j += 8)
    dst[(size_t)(c0 + ty + j) * R + r0 + tx] = tile[tx][ty + j];
}

// ---- fused vectorized NeoX rotary on Q [16][S][128] and K [4][S][128]
__global__ void rope_qk_k(bf16_t* __restrict__ Qb, bf16_t* __restrict__ Kb,
                          const float2* __restrict__ tab, float qscale) {
  int tid = blockIdx.x * 256 + threadIdx.x;
  int row = tid >> 4;
  int i = (tid & 15) * 4;
  bf16_t* base; float scale;
  if (row < NH * S) { base = Qb + (size_t)row * DH; scale = qscale; }
  else { base = Kb + (size_t)(row - NH * S) * DH; scale = 1.0f; }
  int p = row & (S - 1);
  bf16x4 lo = *(bf16x4*)(base + i);
  bf16x4 hi = *(bf16x4*)(base + i + 64);
  float4 t0 = *(const float4*)(tab + p * 64 + i);      // s0,c0,s1,c1
  float4 t1 = *(const float4*)(tab + p * 64 + i + 2);  // s2,c2,s3,c3
  float sv[4] = {t0.x, t0.z, t1.x, t1.z};
  float cv[4] = {t0.y, t0.w, t1.y, t1.w};
  bf16x4 nlo, nhi;
  #pragma unroll
  for (int j = 0; j < 4; ++j) {
    float a = (float)lo[j], b = (float)hi[j];
    nlo[j] = (bf16_t)((a * cv[j] - b * sv[j]) * scale);
    nhi[j] = (bf16_t)((b * cv[j] + a * sv[j]) * scale);
  }
  *(bf16x4*)(base + i) = nlo;
  *(bf16x4*)(base + i + 64) = nhi;
}

// ---- fused QKV projection GEMM: BM=128, BN=64, BK=64, 768 blocks (3/CU).
// nb<32: Q (xq*wqT), nb in [32,40): K, nb in [40,48): V.
// Output head-split bf16: dst[((col>>7)*S + row)*128 + (col&127)] + bias.
__global__ __launch_bounds__(256)
void proj_gemm_k(const bf16_t* __restrict__ xq, const bf16_t* __restrict__ xk,
                 const bf16_t* __restrict__ xv, const bf16_t* __restrict__ wqT,
                 const bf16_t* __restrict__ wkT, const bf16_t* __restrict__ wvT,
                 const float* __restrict__ bQ, const float* __restrict__ bK,
                 const float* __restrict__ bV, bf16_t* __restrict__ Qb,
                 bf16_t* __restrict__ Kb, bf16_t* __restrict__ Vb) {
  const int nb = blockIdx.x;
  const int m0 = blockIdx.y * 128;
  const bf16_t* A; const bf16_t* B; const float* bias; bf16_t* dst; int ncol0;
  if (nb < 32)      { A = xq; B = wqT; bias = bQ; dst = Qb; ncol0 = nb * 64; }
  else if (nb < 40) { A = xk; B = wkT; bias = bK; dst = Kb; ncol0 = (nb - 32) * 64; }
  else              { A = xv; B = wvT; bias = bV; dst = Vb; ncol0 = (nb - 40) * 64; }
  const int K = 2048;
  const int t = threadIdx.x;
  const int lane = t & 63, w = t >> 6;
  const int l15 = lane & 15, lg = lane >> 4;
  const int wr = (w >> 1) * 64, wc = (w & 1) * 32;

  __shared__ bf16_t lA[2][128 * 64];
  __shared__ bf16_t lB[2][64 * 64];

  f32x4 acc[4][2] = {};
  const int srow = t >> 3;
  const int sslot = t & 7;

  auto stage = [&](int buf, int kt) {
    #pragma unroll
    for (int i = 0; i < 4; ++i) {
      int row = i * 32 + srow;
      int ss = sslot ^ (row & 7);
      gload_lds16(A + (size_t)(m0 + row) * K + kt * 64 + ss * 8,
                  (void*)(&lA[buf][0] + i * 2048 + t * 8));
    }
    #pragma unroll
    for (int i = 0; i < 2; ++i) {
      int row = i * 32 + srow;
      int ss = sslot ^ (row & 7);
      gload_lds16(B + (size_t)(ncol0 + row) * K + kt * 64 + ss * 8,
                  (void*)(&lB[buf][0] + i * 2048 + t * 8));
    }
  };

  const int nk = K >> 6;
  stage(0, 0);
  for (int kt = 0; kt < nk; ++kt) {
    const int cur = kt & 1;
    if (kt + 1 < nk) {
      stage(cur ^ 1, kt + 1);
      wait_vmcnt<6>();
    } else {
      wait_vmcnt<0>();
    }
    __builtin_amdgcn_s_barrier();
    #pragma unroll
    for (int kk = 0; kk < 2; ++kk) {
      bf16x8 af[4], bfv[2];
      #pragma unroll
      for (int f = 0; f < 4; ++f) {
        int row = wr + f * 16 + l15;
        int slot = kk * 4 + lg;
        af[f] = *(const bf16x8*)(&lA[cur][0] + row * 64 + ((slot ^ (row & 7)) * 8));
      }
      #pragma unroll
      for (int f = 0; f < 2; ++f) {
        int row = wc + f * 16 + l15;
        int slot = kk * 4 + lg;
        bfv[f] = *(const bf16x8*)(&lB[cur][0] + row * 64 + ((slot ^ (row & 7)) * 8));
      }
      #pragma unroll
      for (int fm = 0; fm < 4; ++fm)
        #pragma unroll
        for (int fn = 0; fn < 2; ++fn)
          acc[fm][fn] = MFMA16(af[fm], bfv[fn], acc[fm][fn]);
    }
    wait_lgkm0();
    __builtin_amdgcn_s_barrier();
  }

  #pragma unroll
  for (int fm = 0; fm < 4; ++fm) {
    int rowb = m0 + wr + fm * 16 + lg * 4;
    #pragma unroll
    for (int fn = 0; fn < 2; ++fn) {
      int col = ncol0 + wc + fn * 16 + l15;
      float bb = bias[col];
      #pragma unroll
      for (int r = 0; r < 4; ++r) {
        float v = acc[fm][fn][r] + bb;
        int rr = rowb + r;
        dst[((size_t)(col >> 7) * S + rr) * DH + (col & 127)] = (bf16_t)v;
      }
    }
  }
}

// ---- O-projection GEMM: BM=128, BN=64, f32 output [M][2048] + bO[col]
__global__ __launch_bounds__(256)
void gemm_o_k(const bf16_t* __restrict__ A, const bf16_t* __restrict__ B,
              const float* __restrict__ bias, float* __restrict__ Cout) {
  const int ncol0 = blockIdx.x * 64;
  const int m0 = blockIdx.y * 128;
  const int K = 2048;
  const int t = threadIdx.x;
  const int lane = t & 63, w = t >> 6;
  const int l15 = lane & 15, lg = lane >> 4;
  const int wr = (w >> 1) * 64, wc = (w & 1) * 32;

  __shared__ bf16_t lA[2][128 * 64];
  __shared__ bf16_t lB[2][64 * 64];

  f32x4 acc[4][2] = {};
  const int srow = t >> 3;
  const int sslot = t & 7;

  auto stage = [&](int buf, int kt) {
    #pragma unroll
    for (int i = 0; i < 4; ++i) {
      int row = i * 32 + srow;
      int ss = sslot ^ (row & 7);
      gload_lds16(A + (size_t)(m0 + row) * K + kt * 64 + ss * 8,
                  (void*)(&lA[buf][0] + i * 2048 + t * 8));
    }
    #pragma unroll
    for (int i = 0; i < 2; ++i) {
      int row = i * 32 + srow;
      int ss = sslot ^ (row & 7);
      gload_lds16(B + (size_t)(ncol0 + row) * K + kt * 64 + ss * 8,
                  (void*)(&lB[buf][0] + i * 2048 + t * 8));
    }
  };

  const int nk = K >> 6;
  stage(0, 0);
  for (int kt = 0; kt < nk; ++kt) {
    const int cur = kt & 1;
    if (kt + 1 < nk) {
      stage(cur ^ 1, kt + 1);
      wait_vmcnt<6>();
    } else {
      wait_vmcnt<0>();
    }
    __builtin_amdgcn_s_barrier();
    #pragma unroll
    for (int kk = 0; kk < 2; ++kk) {
      bf16x8 af[4], bfv[2];
      #pragma unroll
      for (int f = 0; f < 4; ++f) {
        int row = wr + f * 16 + l15;
        int slot = kk * 4 + lg;
        af[f] = *(const bf16x8*)(&lA[cur][0] + row * 64 + ((slot ^ (row & 7)) * 8));
      }
      #pragma unroll
      for (int f = 0; f < 2; ++f) {
        int row = wc + f * 16 + l15;
        int slot = kk * 4 + lg;
        bfv[f] = *(const bf16x8*)(&lB[cur][0] + row * 64 + ((slot ^ (row & 7)) * 8));
      }
      #pragma unroll
      for (int fm = 0; fm < 4; ++fm)
        #pragma unroll
        for (int fn = 0; fn < 2; ++fn)
          acc[fm][fn] = MFMA16(af[fm], bfv[fn], acc[fm][fn]);
    }
    wait_lgkm0();
    __builtin_amdgcn_s_barrier();
  }

  #pragma unroll
  for (int fm = 0; fm < 4; ++fm) {
    int rowb = m0 + wr + fm * 16 + lg * 4;
    #pragma unroll
    for (int fn = 0; fn < 2; ++fn) {
      int col = ncol0 + wc + fn * 16 + l15;
      float bb = bias[col];
      #pragma unroll
      for (int r = 0; r < 4; ++r)
        Cout[(size_t)(rowb + r) * DM + col] = acc[fm][fn][r] + bb;
    }
  }
}

// ---- flash attention, double-buffered K/V, counted vmcnt, balanced 1D grid,
// defer-max (THR=8 in exp2 domain), setprio around MFMA clusters.
__global__ __launch_bounds__(256)
void attn_k(const bf16_t* __restrict__ Q, const bf16_t* __restrict__ K,
            const bf16_t* __restrict__ Vt, bf16_t* __restrict__ Z) {
  const int lin = blockIdx.x;         // 0..511
  const int h = lin & 15;
  const int ip = lin >> 4;            // 0..31
  const int qblk = (ip < 16) ? ip : 47 - ip;  // pair lin, lin+256 -> weights sum 33
  const int q0 = qblk * 64;
  const int hkv = h >> 2;
  const int t = threadIdx.x;
  const int lane = t & 63, w = t >> 6;
  const int l15 = lane & 15, lg = lane >> 4;

  __shared__ bf16_t lK[2][64 * 128];    // [key][d], 16 slots, slot ^= row&15
  __shared__ bf16_t lV[2][128 * 64];    // [d][key], 8 slots, slot ^= row&7
  __shared__ bf16_t lP[4][16 * 64];     // per-wave P[q][key], 8 slots, slot ^= q&7

  const int qrow = q0 + w * 16 + l15;   // this lane's softmax row
  bf16x8 qf[4];
  #pragma unroll
  for (int kk = 0; kk < 4; ++kk)
    qf[kk] = *(const bf16x8*)(Q + ((size_t)h * S + qrow) * DH + kk * 32 + lg * 8);

  auto stageKV = [&](int buf, int kt) {
    #pragma unroll
    for (int i = 0; i < 4; ++i) {
      int row = i * 16 + (t >> 4);
      int ss = (t & 15) ^ (row & 15);
      gload_lds16(K + ((size_t)hkv * S + kt * 64 + row) * DH + ss * 8,
                  (void*)(&lK[buf][0] + i * 2048 + t * 8));
    }
    #pragma unroll
    for (int i = 0; i < 4; ++i) {
      int row = i * 32 + (t >> 3);
      int ss = (t & 7) ^ (row & 7);
      gload_lds16(Vt + ((size_t)hkv * DH + row) * S + kt * 64 + ss * 8,
                  (void*)(&lV[buf][0] + i * 2048 + t * 8));
    }
  };

  f32x4 oacc[8] = {};
  float m_run = -1e30f, l_run = 0.f;

  const int ktmax = q0 >> 6;
  stageKV(0, 0);
  for (int kt = 0; kt <= ktmax; ++kt) {
    const int cur = kt & 1;
    if (kt < ktmax) {
      stageKV(cur ^ 1, kt + 1);
      wait_vmcnt<8>();
    } else {
      wait_vmcnt<0>();
    }
    __builtin_amdgcn_s_barrier();

    // S^T tile = K_tile (64x128) * Q^T : lane holds q=l15, keys fm*16+lg*4+r
    f32x4 sacc[4] = {};
    __builtin_amdgcn_s_setprio(1);
    #pragma unroll
    for (int kk = 0; kk < 4; ++kk) {
      #pragma unroll
      for (int fm = 0; fm < 4; ++fm) {
        int row = fm * 16 + l15;
        int slot = kk * 4 + lg;
        bf16x8 kf = *(const bf16x8*)(&lK[cur][0] + row * 128 + ((slot ^ (row & 15)) * 8));
        sacc[fm] = MFMA16(kf, qf[kk], sacc[fm]);
      }
    }
    __builtin_amdgcn_s_setprio(0);

    const bool diag = (kt == ktmax);
    float smax = -1e30f;
    #pragma unroll
    for (int fm = 0; fm < 4; ++fm) {
      #pragma unroll
      for (int r = 0; r < 4; ++r) {
        float s = sacc[fm][r];
        if (diag) {
          int keyg = kt * 64 + fm * 16 + lg * 4 + r;
          if (keyg > qrow) s = -1e30f;
        }
        sacc[fm][r] = s;
        smax = fmaxf(smax, s);
      }
    }
    smax = fmaxf(smax, __shfl_xor(smax, 16));
    smax = fmaxf(smax, __shfl_xor(smax, 32));

    // defer-max: skip rescale when per-tile max growth <= 8 (exp2 domain)
    float m_new, alpha;
    bool noresc = __all(smax - m_run <= 8.0f);
    if (noresc) {
      m_new = m_run;
      alpha = 1.0f;
    } else {
      m_new = fmaxf(m_run, smax);
      alpha = exp2f(m_run - m_new);
    }

    float psum = 0.f;
    #pragma unroll
    for (int fm = 0; fm < 4; ++fm) {
      bf16x4 pk;
      #pragma unroll
      for (int r = 0; r < 4; ++r) {
        float p = exp2f(sacc[fm][r] - m_new);
        psum += p;
        pk[r] = (bf16_t)p;
      }
      int slot = fm * 2 + (lg >> 1);
      char* dst = (char*)(&lP[w][0]) + l15 * 128 + ((slot ^ (l15 & 7)) * 16) + ((lg & 1) * 8);
      *(bf16x4*)dst = pk;
    }
    psum += __shfl_xor(psum, 16);
    psum += __shfl_xor(psum, 32);
    l_run = l_run * alpha + psum;
    m_run = m_new;

    if (!noresc) {
      // rescale O (rows lg*4+r need alpha of q-lane lg*4+r)
      #pragma unroll
      for (int r = 0; r < 4; ++r) {
        float ar = __shfl(alpha, lg * 4 + r);
        #pragma unroll
        for (int n = 0; n < 8; ++n) oacc[n][r] *= ar;
      }
    }

    // O += P (16x64) * V (64x128)
    __builtin_amdgcn_s_setprio(1);
    #pragma unroll
    for (int kk2 = 0; kk2 < 2; ++kk2) {
      int pslot = kk2 * 4 + lg;
      bf16x8 pf = *(const bf16x8*)((char*)(&lP[w][0]) + l15 * 128 + ((pslot ^ (l15 & 7)) * 16));
      #pragma unroll
      for (int n = 0; n < 8; ++n) {
        int vrow = n * 16 + l15;
        int vslot = kk2 * 4 + lg;
        bf16x8 vf = *(const bf16x8*)(&lV[cur][0] + vrow * 64 + ((vslot ^ (vrow & 7)) * 8));
        oacc[n] = MFMA16(pf, vf, oacc[n]);
      }
    }
    __builtin_amdgcn_s_setprio(0);
    wait_lgkm0();
    __builtin_amdgcn_s_barrier();
  }

  #pragma unroll
  for (int r = 0; r < 4; ++r) {
    float lr = __shfl(l_run, lg * 4 + r);
    float inv = 1.0f / lr;
    int qg = q0 + w * 16 + lg * 4 + r;
    #pragma unroll
    for (int n = 0; n < 8; ++n) {
      int d = n * 16 + l15;
      Z[(size_t)qg * DM + h * DH + d] = (bf16_t)(oacc[n][r] * inv);
    }
  }
}

extern "C" void kernel_launch(void* const* d_in, const int* in_sizes, int n_in,
                              void* d_out, int out_size, void* d_ws, size_t ws_size,
                              hipStream_t stream) {
  (void)in_sizes; (void)n_in; (void)out_size; (void)ws_size;
  const float* Xq = (const float*)d_in[0];
  const float* Xk = (const float*)d_in[1];
  const float* Xv = (const float*)d_in[2];
  const float* WQ = (const float*)d_in[3];
  const float* bQ = (const float*)d_in[4];
  const float* WK = (const float*)d_in[5];
  const float* bK = (const float*)d_in[6];
  const float* WV = (const float*)d_in[7];
  const float* bV = (const float*)d_in[8];
  const float* WO = (const float*)d_in[9];
  const float* bO = (const float*)d_in[10];

  char* w = (char*)d_ws;
  float2* tab = (float2*)w;  // 2048*64*8 = 1 MiB
  bf16_t* xq  = (bf16_t*)(w + (1 << 20));
  bf16_t* xk  = xq + 4194304;
  bf16_t* xv  = xk + 4194304;
  bf16_t* wqT = xv + 4194304;   // [2048][2048]: row h*128+d, col k
  bf16_t* wkT = wqT + 4194304;  // [512][2048]
  bf16_t* wvT = wkT + 1048576;  // [512][2048]
  bf16_t* woT = wvT + 1048576;  // [2048][2048]: row m, col h*128+d
  bf16_t* Qb  = woT + 4194304;  // [16][2048][128]
  bf16_t* Kb  = Qb + 4194304;   // [4][2048][128]
  bf16_t* Vb  = Kb + 1048576;   // [4][2048][128]
  bf16_t* Vtb = Vb + 1048576;   // [4][128][2048]
  bf16_t* Zb  = Vtb + 1048576;  // [2048][2048]

  rope_table_k<<<dim3(S), dim3(64), 0, stream>>>(tab);
  cvt3_k<<<dim3(12288), dim3(256), 0, stream>>>(Xq, Xk, Xv, xq, xk, xv);
  // W_Q (16,2048,128): out[(h*128+d)*2048 + k]
  transpose_w_k<<<dim3(4, 64, 16), dim3(32, 8), 0, stream>>>(WQ, wqT, 2048, 128, 128, 0, 2048);
  transpose_wkv_k<<<dim3(4, 64, 8), dim3(32, 8), 0, stream>>>(WK, WV, wkT, wvT);
  // W_O (16,128,2048): out[m*2048 + h*128 + d]
  transpose_w_k<<<dim3(64, 4, 16), dim3(32, 8), 0, stream>>>(WO, woT, 128, 2048, 0, 128, 2048);

  proj_gemm_k<<<dim3(48, 16), dim3(256), 0, stream>>>(xq, xk, xv, wqT, wkT, wvT,
                                                      bQ, bK, bV, Qb, Kb, Vb);

  transpose_v_k<<<dim3(4, 64, 4), dim3(32, 8), 0, stream>>>(Vb, Vtb, 2048, 128);

  const float qscale = 1.4426950408889634f / sqrtf(128.0f);  // log2e / sqrt(D_HEAD)
  rope_qk_k<<<dim3(2560), dim3(256), 0, stream>>>(Qb, Kb, tab, qscale);

  attn_k<<<dim3(512), dim3(256), 0, stream>>>(Qb, Kb, Vtb, Zb);

  gemm_o_k<<<dim3(32, 16), dim3(256), 0, stream>>>(Zb, woT, bO, (float*)d_out);
}

// Round 4
// 159.287 us; speedup vs baseline: 1.9822x; 1.0688x over previous
//
#include <hip/hip_runtime.h>
#include <hip/hip_bf16.h>
#include <stdint.h>
#include <math.h>

typedef __bf16 bf16_t;
typedef __attribute__((ext_vector_type(8))) __bf16 bf16x8;
typedef __attribute__((ext_vector_type(4))) __bf16 bf16x4;
typedef __attribute__((ext_vector_type(4))) float f32x4;

static constexpr int S = 2048;
static constexpr int DM = 2048;
static constexpr int NH = 16;
static constexpr int NKV = 4;
static constexpr int DH = 128;

#define MFMA16(a, b, c) __builtin_amdgcn_mfma_f32_16x16x32_bf16((a), (b), (c), 0, 0, 0)

__device__ __forceinline__ void gload_lds16(const void* g, void* l) {
  __builtin_amdgcn_global_load_lds((__attribute__((address_space(1))) void*)(g),
                                   (__attribute__((address_space(3))) void*)(l), 16, 0, 0);
}

template <int N>
__device__ __forceinline__ void wait_vmcnt() {
  asm volatile("s_waitcnt vmcnt(%0)" :: "n"(N) : "memory");
}
__device__ __forceinline__ void wait_lgkm0() {
  asm volatile("s_waitcnt lgkmcnt(0)" ::: "memory");
}

// ---- RoPE table: [S][64] float2 {sin, cos}; angle = p * base^(-j/64)
__global__ void rope_table_k(float2* __restrict__ tab) {
  int p = blockIdx.x;
  int j = threadIdx.x;
  double inv = exp2(-(double)j * 13.287712379549449 / 64.0);  // log2(10000)
  double ang = (double)p * inv;
  tab[p * 64 + j] = make_float2((float)sin(ang), (float)cos(ang));
}

// ---- fused f32 -> bf16 convert of Xq, Xk, Xv
__global__ void cvt3_k(const float* __restrict__ Xq, const float* __restrict__ Xk,
                       const float* __restrict__ Xv, bf16_t* __restrict__ xq,
                       bf16_t* __restrict__ xk, bf16_t* __restrict__ xv) {
  int i = (blockIdx.x * 256 + threadIdx.x) * 4;
  const float* in; bf16_t* out; int off;
  if (i < 4194304) { in = Xq; out = xq; off = i; }
  else if (i < 8388608) { in = Xk; out = xk; off = i - 4194304; }
  else { in = Xv; out = xv; off = i - 8388608; }
  f32x4 v = *(const f32x4*)(in + off);
  bf16x4 o;
  o[0] = (bf16_t)v[0]; o[1] = (bf16_t)v[1]; o[2] = (bf16_t)v[2]; o[3] = (bf16_t)v[3];
  *(bf16x4*)(out + off) = o;
}

// ---- weight transpose+convert: in[b][r][c] f32 -> out[(b*rb + c)*ldo + b*cb + r] bf16
__global__ void transpose_w_k(const float* __restrict__ in, bf16_t* __restrict__ out,
                              int R, int C, int rb, int cb, int ldo) {
  __shared__ float tile[32][33];
  int b = blockIdx.z;
  int c0 = blockIdx.x * 32, r0 = blockIdx.y * 32;
  int tx = threadIdx.x, ty = threadIdx.y;  // 32 x 8
  const float* src = in + (size_t)b * R * C;
  #pragma unroll
  for (int j = 0; j < 32; j += 8)
    tile[ty + j][tx] = src[(size_t)(r0 + ty + j) * C + c0 + tx];
  __syncthreads();
  #pragma unroll
  for (int j = 0; j < 32; j += 8) {
    int c = c0 + ty + j;
    int r = r0 + tx;
    out[(size_t)(b * rb + c) * ldo + b * cb + r] = (bf16_t)tile[tx][ty + j];
  }
}

// ---- fused WK+WV transpose: z in [0,8), b=z&3, sel=z>>2
__global__ void transpose_wkv_k(const float* __restrict__ WK, const float* __restrict__ WV,
                                bf16_t* __restrict__ wkT, bf16_t* __restrict__ wvT) {
  __shared__ float tile[32][33];
  int z = blockIdx.z;
  int b = z & 3;
  const float* in = (z < 4) ? WK : WV;
  bf16_t* out = (z < 4) ? wkT : wvT;
  int c0 = blockIdx.x * 32, r0 = blockIdx.y * 32;
  int tx = threadIdx.x, ty = threadIdx.y;
  const float* src = in + (size_t)b * 2048 * 128;
  #pragma unroll
  for (int j = 0; j < 32; j += 8)
    tile[ty + j][tx] = src[(size_t)(r0 + ty + j) * 128 + c0 + tx];
  __syncthreads();
  #pragma unroll
  for (int j = 0; j < 32; j += 8) {
    int c = c0 + ty + j;
    int r = r0 + tx;
    out[(size_t)(b * 128 + c) * 2048 + r] = (bf16_t)tile[tx][ty + j];
  }
}

// ---- fused vectorized NeoX rotary on Q [16][S][128] and K [4][S][128]
__global__ void rope_qk_k(bf16_t* __restrict__ Qb, bf16_t* __restrict__ Kb,
                          const float2* __restrict__ tab, float qscale) {
  int tid = blockIdx.x * 256 + threadIdx.x;
  int row = tid >> 4;
  int i = (tid & 15) * 4;
  bf16_t* base; float scale;
  if (row < NH * S) { base = Qb + (size_t)row * DH; scale = qscale; }
  else { base = Kb + (size_t)(row - NH * S) * DH; scale = 1.0f; }
  int p = row & (S - 1);
  bf16x4 lo = *(bf16x4*)(base + i);
  bf16x4 hi = *(bf16x4*)(base + i + 64);
  float4 t0 = *(const float4*)(tab + p * 64 + i);      // s0,c0,s1,c1
  float4 t1 = *(const float4*)(tab + p * 64 + i + 2);  // s2,c2,s3,c3
  float sv[4] = {t0.x, t0.z, t1.x, t1.z};
  float cv[4] = {t0.y, t0.w, t1.y, t1.w};
  bf16x4 nlo, nhi;
  #pragma unroll
  for (int j = 0; j < 4; ++j) {
    float a = (float)lo[j], b = (float)hi[j];
    nlo[j] = (bf16_t)((a * cv[j] - b * sv[j]) * scale);
    nhi[j] = (bf16_t)((b * cv[j] + a * sv[j]) * scale);
  }
  *(bf16x4*)(base + i) = nlo;
  *(bf16x4*)(base + i + 64) = nhi;
}

// ---- fused QKV projection GEMM: BM=128, BN=64, BK=64, 768 blocks (3/CU).
// nb<32: Q, nb in [32,40): K, nb in [40,48): V (V written TRANSPOSED to Vt[h][d][p]).
__global__ __launch_bounds__(256)
void proj_gemm_k(const bf16_t* __restrict__ xq, const bf16_t* __restrict__ xk,
                 const bf16_t* __restrict__ xv, const bf16_t* __restrict__ wqT,
                 const bf16_t* __restrict__ wkT, const bf16_t* __restrict__ wvT,
                 const float* __restrict__ bQ, const float* __restrict__ bK,
                 const float* __restrict__ bV, bf16_t* __restrict__ Qb,
                 bf16_t* __restrict__ Kb, bf16_t* __restrict__ Vt) {
  const int nb = blockIdx.x;
  const int m0 = blockIdx.y * 128;
  const bf16_t* A; const bf16_t* B; const float* bias; bf16_t* dst; int ncol0;
  bool vmode = false;
  if (nb < 32)      { A = xq; B = wqT; bias = bQ; dst = Qb; ncol0 = nb * 64; }
  else if (nb < 40) { A = xk; B = wkT; bias = bK; dst = Kb; ncol0 = (nb - 32) * 64; }
  else              { A = xv; B = wvT; bias = bV; dst = Vt; ncol0 = (nb - 40) * 64; vmode = true; }
  const int K = 2048;
  const int t = threadIdx.x;
  const int lane = t & 63, w = t >> 6;
  const int l15 = lane & 15, lg = lane >> 4;
  const int wr = (w >> 1) * 64, wc = (w & 1) * 32;

  __shared__ bf16_t lA[2][128 * 64];
  __shared__ bf16_t lB[2][64 * 64];

  f32x4 acc[4][2] = {};
  const int srow = t >> 3;
  const int sslot = t & 7;

  auto stage = [&](int buf, int kt) {
    #pragma unroll
    for (int i = 0; i < 4; ++i) {
      int row = i * 32 + srow;
      int ss = sslot ^ (row & 7);
      gload_lds16(A + (size_t)(m0 + row) * K + kt * 64 + ss * 8,
                  (void*)(&lA[buf][0] + i * 2048 + t * 8));
    }
    #pragma unroll
    for (int i = 0; i < 2; ++i) {
      int row = i * 32 + srow;
      int ss = sslot ^ (row & 7);
      gload_lds16(B + (size_t)(ncol0 + row) * K + kt * 64 + ss * 8,
                  (void*)(&lB[buf][0] + i * 2048 + t * 8));
    }
  };

  const int nk = K >> 6;
  stage(0, 0);
  for (int kt = 0; kt < nk; ++kt) {
    const int cur = kt & 1;
    if (kt + 1 < nk) {
      stage(cur ^ 1, kt + 1);
      wait_vmcnt<6>();
    } else {
      wait_vmcnt<0>();
    }
    __builtin_amdgcn_s_barrier();
    #pragma unroll
    for (int kk = 0; kk < 2; ++kk) {
      bf16x8 af[4], bfv[2];
      #pragma unroll
      for (int f = 0; f < 4; ++f) {
        int row = wr + f * 16 + l15;
        int slot = kk * 4 + lg;
        af[f] = *(const bf16x8*)(&lA[cur][0] + row * 64 + ((slot ^ (row & 7)) * 8));
      }
      #pragma unroll
      for (int f = 0; f < 2; ++f) {
        int row = wc + f * 16 + l15;
        int slot = kk * 4 + lg;
        bfv[f] = *(const bf16x8*)(&lB[cur][0] + row * 64 + ((slot ^ (row & 7)) * 8));
      }
      #pragma unroll
      for (int fm = 0; fm < 4; ++fm)
        #pragma unroll
        for (int fn = 0; fn < 2; ++fn)
          acc[fm][fn] = MFMA16(af[fm], bfv[fn], acc[fm][fn]);
    }
    wait_lgkm0();
    __builtin_amdgcn_s_barrier();
  }

  #pragma unroll
  for (int fm = 0; fm < 4; ++fm) {
    int rowb = m0 + wr + fm * 16 + lg * 4;
    #pragma unroll
    for (int fn = 0; fn < 2; ++fn) {
      int col = ncol0 + wc + fn * 16 + l15;
      float bb = bias[col];
      if (vmode) {
        // V: write transposed Vt[col][p], 4 consecutive p -> one 8B store
        bf16x4 pk;
        #pragma unroll
        for (int r = 0; r < 4; ++r) pk[r] = (bf16_t)(acc[fm][fn][r] + bb);
        *(bf16x4*)(dst + (size_t)col * S + rowb) = pk;
      } else {
        #pragma unroll
        for (int r = 0; r < 4; ++r) {
          float v = acc[fm][fn][r] + bb;
          dst[((size_t)(col >> 7) * S + (rowb + r)) * DH + (col & 127)] = (bf16_t)v;
        }
      }
    }
  }
}

// ---- O-projection GEMM: BM=128, BN=64, f32 output [M][2048] + bO[col]
__global__ __launch_bounds__(256)
void gemm_o_k(const bf16_t* __restrict__ A, const bf16_t* __restrict__ B,
              const float* __restrict__ bias, float* __restrict__ Cout) {
  const int ncol0 = blockIdx.x * 64;
  const int m0 = blockIdx.y * 128;
  const int K = 2048;
  const int t = threadIdx.x;
  const int lane = t & 63, w = t >> 6;
  const int l15 = lane & 15, lg = lane >> 4;
  const int wr = (w >> 1) * 64, wc = (w & 1) * 32;

  __shared__ bf16_t lA[2][128 * 64];
  __shared__ bf16_t lB[2][64 * 64];

  f32x4 acc[4][2] = {};
  const int srow = t >> 3;
  const int sslot = t & 7;

  auto stage = [&](int buf, int kt) {
    #pragma unroll
    for (int i = 0; i < 4; ++i) {
      int row = i * 32 + srow;
      int ss = sslot ^ (row & 7);
      gload_lds16(A + (size_t)(m0 + row) * K + kt * 64 + ss * 8,
                  (void*)(&lA[buf][0] + i * 2048 + t * 8));
    }
    #pragma unroll
    for (int i = 0; i < 2; ++i) {
      int row = i * 32 + srow;
      int ss = sslot ^ (row & 7);
      gload_lds16(B + (size_t)(ncol0 + row) * K + kt * 64 + ss * 8,
                  (void*)(&lB[buf][0] + i * 2048 + t * 8));
    }
  };

  const int nk = K >> 6;
  stage(0, 0);
  for (int kt = 0; kt < nk; ++kt) {
    const int cur = kt & 1;
    if (kt + 1 < nk) {
      stage(cur ^ 1, kt + 1);
      wait_vmcnt<6>();
    } else {
      wait_vmcnt<0>();
    }
    __builtin_amdgcn_s_barrier();
    #pragma unroll
    for (int kk = 0; kk < 2; ++kk) {
      bf16x8 af[4], bfv[2];
      #pragma unroll
      for (int f = 0; f < 4; ++f) {
        int row = wr + f * 16 + l15;
        int slot = kk * 4 + lg;
        af[f] = *(const bf16x8*)(&lA[cur][0] + row * 64 + ((slot ^ (row & 7)) * 8));
      }
      #pragma unroll
      for (int f = 0; f < 2; ++f) {
        int row = wc + f * 16 + l15;
        int slot = kk * 4 + lg;
        bfv[f] = *(const bf16x8*)(&lB[cur][0] + row * 64 + ((slot ^ (row & 7)) * 8));
      }
      #pragma unroll
      for (int fm = 0; fm < 4; ++fm)
        #pragma unroll
        for (int fn = 0; fn < 2; ++fn)
          acc[fm][fn] = MFMA16(af[fm], bfv[fn], acc[fm][fn]);
    }
    wait_lgkm0();
    __builtin_amdgcn_s_barrier();
  }

  #pragma unroll
  for (int fm = 0; fm < 4; ++fm) {
    int rowb = m0 + wr + fm * 16 + lg * 4;
    #pragma unroll
    for (int fn = 0; fn < 2; ++fn) {
      int col = ncol0 + wc + fn * 16 + l15;
      float bb = bias[col];
      #pragma unroll
      for (int r = 0; r < 4; ++r)
        Cout[(size_t)(rowb + r) * DM + col] = acc[fm][fn][r] + bb;
    }
  }
}

// ---- split-flash attention: 768 blocks, weight-descending dispatch order.
// bid = g*16 + h; g -> (qb, chunk). Units qb<16: single chunk -> write Z.
// qb>=16: chunk0 = tiles 0..15, chunk1 = tiles 16..qb -> write f32 partials.
__global__ __launch_bounds__(256)
void attn_k(const bf16_t* __restrict__ Q, const bf16_t* __restrict__ K,
            const bf16_t* __restrict__ Vt, bf16_t* __restrict__ Z,
            float* __restrict__ Opart, float* __restrict__ mpart,
            float* __restrict__ lpart) {
  const int bid = blockIdx.x;
  const int h = bid & 15;
  const int g = bid >> 4;  // 0..47, weight-descending
  int qb, ch;
  if (g <= 16) { qb = 31 - g; ch = 0; }
  else if (g == 17) { qb = 31; ch = 1; }
  else {
    int idx = (g - 18) >> 1;
    if (g & 1) { ch = 1; qb = 30 - idx; }
    else { ch = 0; qb = 14 - idx; }
  }
  const int q0 = qb * 64;
  const int hkv = h >> 2;
  const int t = threadIdx.x;
  const int lane = t & 63, w = t >> 6;
  const int l15 = lane & 15, lg = lane >> 4;

  __shared__ bf16_t lK[2][64 * 128];    // [key][d], 16 slots, slot ^= row&15
  __shared__ bf16_t lV[2][128 * 64];    // [d][key], 8 slots, slot ^= row&7
  __shared__ bf16_t lP[4][16 * 64];     // per-wave P[q][key], 8 slots, slot ^= q&7

  const int qrow = q0 + w * 16 + l15;   // this lane's softmax row
  bf16x8 qf[4];
  #pragma unroll
  for (int kk = 0; kk < 4; ++kk)
    qf[kk] = *(const bf16x8*)(Q + ((size_t)h * S + qrow) * DH + kk * 32 + lg * 8);

  auto stageKV = [&](int buf, int kt) {
    #pragma unroll
    for (int i = 0; i < 4; ++i) {
      int row = i * 16 + (t >> 4);
      int ss = (t & 15) ^ (row & 15);
      gload_lds16(K + ((size_t)hkv * S + kt * 64 + row) * DH + ss * 8,
                  (void*)(&lK[buf][0] + i * 2048 + t * 8));
    }
    #pragma unroll
    for (int i = 0; i < 4; ++i) {
      int row = i * 32 + (t >> 3);
      int ss = (t & 7) ^ (row & 7);
      gload_lds16(Vt + ((size_t)hkv * DH + row) * S + kt * 64 + ss * 8,
                  (void*)(&lV[buf][0] + i * 2048 + t * 8));
    }
  };

  f32x4 oacc[8] = {};
  float m_run = -1e30f, l_run = 0.f;

  const int kt0 = ch * 16;
  const int ktend = ch ? qb : ((qb < 15) ? qb : 15);
  stageKV(0, kt0);
  for (int kt = kt0; kt <= ktend; ++kt) {
    const int cur = (kt - kt0) & 1;
    if (kt < ktend) {
      stageKV(cur ^ 1, kt + 1);
      wait_vmcnt<8>();
    } else {
      wait_vmcnt<0>();
    }
    __builtin_amdgcn_s_barrier();

    // S^T tile = K_tile (64x128) * Q^T : lane holds q=l15, keys fm*16+lg*4+r
    f32x4 sacc[4] = {};
    __builtin_amdgcn_s_setprio(1);
    #pragma unroll
    for (int kk = 0; kk < 4; ++kk) {
      #pragma unroll
      for (int fm = 0; fm < 4; ++fm) {
        int row = fm * 16 + l15;
        int slot = kk * 4 + lg;
        bf16x8 kf = *(const bf16x8*)(&lK[cur][0] + row * 128 + ((slot ^ (row & 15)) * 8));
        sacc[fm] = MFMA16(kf, qf[kk], sacc[fm]);
      }
    }
    __builtin_amdgcn_s_setprio(0);

    const bool diag = (kt == qb);
    float smax = -1e30f;
    #pragma unroll
    for (int fm = 0; fm < 4; ++fm) {
      #pragma unroll
      for (int r = 0; r < 4; ++r) {
        float s = sacc[fm][r];
        if (diag) {
          int keyg = kt * 64 + fm * 16 + lg * 4 + r;
          if (keyg > qrow) s = -1e30f;
        }
        sacc[fm][r] = s;
        smax = fmaxf(smax, s);
      }
    }
    smax = fmaxf(smax, __shfl_xor(smax, 16));
    smax = fmaxf(smax, __shfl_xor(smax, 32));

    // defer-max: skip rescale when per-tile max growth <= 8 (exp2 domain)
    float m_new, alpha;
    bool noresc = __all(smax - m_run <= 8.0f);
    if (noresc) {
      m_new = m_run;
      alpha = 1.0f;
    } else {
      m_new = fmaxf(m_run, smax);
      alpha = exp2f(m_run - m_new);
    }

    float psum = 0.f;
    #pragma unroll
    for (int fm = 0; fm < 4; ++fm) {
      bf16x4 pk;
      #pragma unroll
      for (int r = 0; r < 4; ++r) {
        float p = exp2f(sacc[fm][r] - m_new);
        psum += p;
        pk[r] = (bf16_t)p;
      }
      int slot = fm * 2 + (lg >> 1);
      char* dst = (char*)(&lP[w][0]) + l15 * 128 + ((slot ^ (l15 & 7)) * 16) + ((lg & 1) * 8);
      *(bf16x4*)dst = pk;
    }
    psum += __shfl_xor(psum, 16);
    psum += __shfl_xor(psum, 32);
    l_run = l_run * alpha + psum;
    m_run = m_new;

    if (!noresc) {
      #pragma unroll
      for (int r = 0; r < 4; ++r) {
        float ar = __shfl(alpha, lg * 4 + r);
        #pragma unroll
        for (int n = 0; n < 8; ++n) oacc[n][r] *= ar;
      }
    }

    // O += P (16x64) * V (64x128)
    __builtin_amdgcn_s_setprio(1);
    #pragma unroll
    for (int kk2 = 0; kk2 < 2; ++kk2) {
      int pslot = kk2 * 4 + lg;
      bf16x8 pf = *(const bf16x8*)((char*)(&lP[w][0]) + l15 * 128 + ((pslot ^ (l15 & 7)) * 16));
      #pragma unroll
      for (int n = 0; n < 8; ++n) {
        int vrow = n * 16 + l15;
        int vslot = kk2 * 4 + lg;
        bf16x8 vf = *(const bf16x8*)(&lV[cur][0] + vrow * 64 + ((vslot ^ (vrow & 7)) * 8));
        oacc[n] = MFMA16(pf, vf, oacc[n]);
      }
    }
    __builtin_amdgcn_s_setprio(0);
    wait_lgkm0();
    __builtin_amdgcn_s_barrier();
  }

  if (qb < 16) {
    // single chunk: finalize and write Z
    #pragma unroll
    for (int r = 0; r < 4; ++r) {
      float lr = __shfl(l_run, lg * 4 + r);
      float inv = 1.0f / lr;
      int qg = q0 + w * 16 + lg * 4 + r;
      #pragma unroll
      for (int n = 0; n < 8; ++n) {
        int d = n * 16 + l15;
        Z[(size_t)qg * DM + h * DH + d] = (bf16_t)(oacc[n][r] * inv);
      }
    }
  } else {
    const int slot = (h * 16 + (qb - 16)) * 2 + ch;
    float* Op = Opart + (size_t)slot * 8192;
    #pragma unroll
    for (int r = 0; r < 4; ++r) {
      int lr = w * 16 + lg * 4 + r;  // local q-row 0..63
      #pragma unroll
      for (int n = 0; n < 8; ++n)
        Op[lr * 128 + n * 16 + l15] = oacc[n][r];
    }
    if (lg == 0) {
      mpart[slot * 64 + w * 16 + l15] = m_run;
      lpart[slot * 64 + w * 16 + l15] = l_run;
    }
  }
}

// ---- combine: merge 2 partials per (h, qb>=16) unit, write Z bf16
__global__ void combine_k(const float* __restrict__ Opart, const float* __restrict__ mpart,
                          const float* __restrict__ lpart, bf16_t* __restrict__ Z) {
  int idx = blockIdx.x * 256 + threadIdx.x;  // 2M total
  int d = idx & 127;
  int r = (idx >> 7) & 63;
  int qb16 = (idx >> 13) & 15;
  int h = idx >> 17;
  int s0 = (h * 16 + qb16) * 2;
  float m0 = mpart[s0 * 64 + r], m1 = mpart[(s0 + 1) * 64 + r];
  float l0 = lpart[s0 * 64 + r], l1 = lpart[(s0 + 1) * 64 + r];
  float M = fmaxf(m0, m1);
  float a0 = exp2f(m0 - M), a1 = exp2f(m1 - M);
  float L = a0 * l0 + a1 * l1;
  float o0 = Opart[(size_t)s0 * 8192 + r * 128 + d];
  float o1 = Opart[(size_t)(s0 + 1) * 8192 + r * 128 + d];
  int qrow = (16 + qb16) * 64 + r;
  Z[(size_t)qrow * DM + h * DH + d] = (bf16_t)((a0 * o0 + a1 * o1) / L);
}

extern "C" void kernel_launch(void* const* d_in, const int* in_sizes, int n_in,
                              void* d_out, int out_size, void* d_ws, size_t ws_size,
                              hipStream_t stream) {
  (void)in_sizes; (void)n_in; (void)out_size; (void)ws_size;
  const float* Xq = (const float*)d_in[0];
  const float* Xk = (const float*)d_in[1];
  const float* Xv = (const float*)d_in[2];
  const float* WQ = (const float*)d_in[3];
  const float* bQ = (const float*)d_in[4];
  const float* WK = (const float*)d_in[5];
  const float* bK = (const float*)d_in[6];
  const float* WV = (const float*)d_in[7];
  const float* bV = (const float*)d_in[8];
  const float* WO = (const float*)d_in[9];
  const float* bO = (const float*)d_in[10];

  char* w = (char*)d_ws;
  float2* tab = (float2*)w;     // 1 MiB
  bf16_t* xq  = (bf16_t*)(w + (1 << 20));  // 8 MiB
  bf16_t* xk  = xq + 4194304;   // 8 MiB
  bf16_t* xv  = xk + 4194304;   // 8 MiB
  bf16_t* wqT = xv + 4194304;   // 8 MiB
  bf16_t* wkT = wqT + 4194304;  // 2 MiB
  bf16_t* wvT = wkT + 1048576;  // 2 MiB
  bf16_t* woT = wvT + 1048576;  // 8 MiB
  bf16_t* Qb  = woT + 4194304;  // 8 MiB
  bf16_t* Kb  = Qb + 4194304;   // 2 MiB
  bf16_t* Vtb = Kb + 1048576;   // 2 MiB  [4][128][2048]
  bf16_t* Zb  = Vtb + 1048576;  // 8 MiB
  // attn partials overlay xq/xk/xv (dead after proj): 16 MiB + 2*128 KiB
  float* Opart = (float*)xq;             // 512 slots * 8192 f32
  float* mpart = Opart + 512 * 8192;
  float* lpart = mpart + 512 * 64;

  rope_table_k<<<dim3(S), dim3(64), 0, stream>>>(tab);
  cvt3_k<<<dim3(12288), dim3(256), 0, stream>>>(Xq, Xk, Xv, xq, xk, xv);
  transpose_w_k<<<dim3(4, 64, 16), dim3(32, 8), 0, stream>>>(WQ, wqT, 2048, 128, 128, 0, 2048);
  transpose_wkv_k<<<dim3(4, 64, 8), dim3(32, 8), 0, stream>>>(WK, WV, wkT, wvT);
  transpose_w_k<<<dim3(64, 4, 16), dim3(32, 8), 0, stream>>>(WO, woT, 128, 2048, 0, 128, 2048);

  proj_gemm_k<<<dim3(48, 16), dim3(256), 0, stream>>>(xq, xk, xv, wqT, wkT, wvT,
                                                      bQ, bK, bV, Qb, Kb, Vtb);

  const float qscale = 1.4426950408889634f / sqrtf(128.0f);  // log2e / sqrt(D_HEAD)
  rope_qk_k<<<dim3(2560), dim3(256), 0, stream>>>(Qb, Kb, tab, qscale);

  attn_k<<<dim3(768), dim3(256), 0, stream>>>(Qb, Kb, Vtb, Zb, Opart, mpart, lpart);
  combine_k<<<dim3(8192), dim3(256), 0, stream>>>(Opart, mpart, lpart, Zb);

  gemm_o_k<<<dim3(32, 16), dim3(256), 0, stream>>>(Zb, woT, bO, (float*)d_out);
}

// Round 5
// 157.471 us; speedup vs baseline: 2.0051x; 1.0115x over previous
//
#include <hip/hip_runtime.h>
#include <hip/hip_bf16.h>
#include <stdint.h>
#include <math.h>

typedef __bf16 bf16_t;
typedef __attribute__((ext_vector_type(8))) __bf16 bf16x8;
typedef __attribute__((ext_vector_type(4))) __bf16 bf16x4;
typedef __attribute__((ext_vector_type(4))) float f32x4;
typedef __attribute__((ext_vector_type(16))) float f32x16;
typedef unsigned int uint2v __attribute__((ext_vector_type(2)));

static constexpr int S = 2048;
static constexpr int DM = 2048;
static constexpr int NH = 16;
static constexpr int NKV = 4;
static constexpr int DH = 128;

#define MFMA16(a, b, c) __builtin_amdgcn_mfma_f32_16x16x32_bf16((a), (b), (c), 0, 0, 0)
#define MFMA32(a, b, c) __builtin_amdgcn_mfma_f32_32x32x16_bf16((a), (b), (c), 0, 0, 0)

__device__ __forceinline__ void gload_lds16(const void* g, void* l) {
  __builtin_amdgcn_global_load_lds((__attribute__((address_space(1))) void*)(g),
                                   (__attribute__((address_space(3))) void*)(l), 16, 0, 0);
}

template <int N>
__device__ __forceinline__ void wait_vmcnt() {
  asm volatile("s_waitcnt vmcnt(%0)" :: "n"(N) : "memory");
}
__device__ __forceinline__ void wait_lgkm0() {
  asm volatile("s_waitcnt lgkmcnt(0)" ::: "memory");
}

__device__ __forceinline__ unsigned cvtpk(float lo, float hi) {
  unsigned r;
  asm("v_cvt_pk_bf16_f32 %0, %1, %2" : "=v"(r) : "v"(lo), "v"(hi));
  return r;
}
// swap(a,b): a' = {a.lo, b.lo}, b' = {a.hi, b.hi}
__device__ __forceinline__ void plswap2(unsigned& a, unsigned& b) {
  uint2v r = __builtin_amdgcn_permlane32_swap(a, b, false, false);
  a = r[0]; b = r[1];
}
__device__ __forceinline__ float swapred_max(float x) {
  uint2v r = __builtin_amdgcn_permlane32_swap(__float_as_uint(x), __float_as_uint(x), false, false);
  return fmaxf(__uint_as_float(r[0]), __uint_as_float(r[1]));
}
__device__ __forceinline__ float swapred_sum(float x) {
  uint2v r = __builtin_amdgcn_permlane32_swap(__float_as_uint(x), __float_as_uint(x), false, false);
  return __uint_as_float(r[0]) + __uint_as_float(r[1]);
}
// build 32x32x16 A-fragment from 8 per-lane P values (keys (r&3)+8*(r>>2)+4*hi)
__device__ __forceinline__ bf16x8 packfrag(float a0, float a1, float a2, float a3,
                                           float a4, float a5, float a6, float a7) {
  unsigned w0 = cvtpk(a0, a1), w1 = cvtpk(a2, a3);
  unsigned w2 = cvtpk(a4, a5), w3 = cvtpk(a6, a7);
  plswap2(w0, w2); plswap2(w1, w3);
  union { unsigned u[4]; bf16x8 v; } u;
  u.u[0] = w0; u.u[1] = w1; u.u[2] = w2; u.u[3] = w3;
  return u.v;
}

// unit map: 24 units/head, (qb<<1)|ci, descending tile count
__device__ const unsigned char attn_map[24] = {
  (15<<1)|0,(15<<1)|1,(7<<1)|0,(14<<1)|0,(14<<1)|1,(13<<1)|0,(13<<1)|1,(6<<1)|0,
  (12<<1)|0,(12<<1)|1,(5<<1)|0,(11<<1)|0,(11<<1)|1,(10<<1)|0,(10<<1)|1,(9<<1)|0,
  (9<<1)|1,(4<<1)|0,(8<<1)|0,(8<<1)|1,(3<<1)|0,(2<<1)|0,(1<<1)|0,(0<<1)|0};

// ---- RoPE table: [S][64] float2 {sin, cos}; angle = p * base^(-j/64)
__global__ void rope_table_k(float2* __restrict__ tab) {
  int p = blockIdx.x;
  int j = threadIdx.x;
  double inv = exp2(-(double)j * 13.287712379549449 / 64.0);  // log2(10000)
  double ang = (double)p * inv;
  tab[p * 64 + j] = make_float2((float)sin(ang), (float)cos(ang));
}

// ---- fused f32 -> bf16 convert of Xq, Xk, Xv
__global__ void cvt3_k(const float* __restrict__ Xq, const float* __restrict__ Xk,
                       const float* __restrict__ Xv, bf16_t* __restrict__ xq,
                       bf16_t* __restrict__ xk, bf16_t* __restrict__ xv) {
  int i = (blockIdx.x * 256 + threadIdx.x) * 4;
  const float* in; bf16_t* out; int off;
  if (i < 4194304) { in = Xq; out = xq; off = i; }
  else if (i < 8388608) { in = Xk; out = xk; off = i - 4194304; }
  else { in = Xv; out = xv; off = i - 8388608; }
  f32x4 v = *(const f32x4*)(in + off);
  bf16x4 o;
  o[0] = (bf16_t)v[0]; o[1] = (bf16_t)v[1]; o[2] = (bf16_t)v[2]; o[3] = (bf16_t)v[3];
  *(bf16x4*)(out + off) = o;
}

// ---- weight transpose+convert
__global__ void transpose_w_k(const float* __restrict__ in, bf16_t* __restrict__ out,
                              int R, int C, int rb, int cb, int ldo) {
  __shared__ float tile[32][33];
  int b = blockIdx.z;
  int c0 = blockIdx.x * 32, r0 = blockIdx.y * 32;
  int tx = threadIdx.x, ty = threadIdx.y;  // 32 x 8
  const float* src = in + (size_t)b * R * C;
  #pragma unroll
  for (int j = 0; j < 32; j += 8)
    tile[ty + j][tx] = src[(size_t)(r0 + ty + j) * C + c0 + tx];
  __syncthreads();
  #pragma unroll
  for (int j = 0; j < 32; j += 8) {
    int c = c0 + ty + j;
    int r = r0 + tx;
    out[(size_t)(b * rb + c) * ldo + b * cb + r] = (bf16_t)tile[tx][ty + j];
  }
}

// ---- fused WK+WV transpose
__global__ void transpose_wkv_k(const float* __restrict__ WK, const float* __restrict__ WV,
                                bf16_t* __restrict__ wkT, bf16_t* __restrict__ wvT) {
  __shared__ float tile[32][33];
  int z = blockIdx.z;
  int b = z & 3;
  const float* in = (z < 4) ? WK : WV;
  bf16_t* out = (z < 4) ? wkT : wvT;
  int c0 = blockIdx.x * 32, r0 = blockIdx.y * 32;
  int tx = threadIdx.x, ty = threadIdx.y;
  const float* src = in + (size_t)b * 2048 * 128;
  #pragma unroll
  for (int j = 0; j < 32; j += 8)
    tile[ty + j][tx] = src[(size_t)(r0 + ty + j) * 128 + c0 + tx];
  __syncthreads();
  #pragma unroll
  for (int j = 0; j < 32; j += 8) {
    int c = c0 + ty + j;
    int r = r0 + tx;
    out[(size_t)(b * 128 + c) * 2048 + r] = (bf16_t)tile[tx][ty + j];
  }
}

// ---- fused vectorized NeoX rotary on Q [16][S][128] and K [4][S][128]
__global__ void rope_qk_k(bf16_t* __restrict__ Qb, bf16_t* __restrict__ Kb,
                          const float2* __restrict__ tab, float qscale) {
  int tid = blockIdx.x * 256 + threadIdx.x;
  int row = tid >> 4;
  int i = (tid & 15) * 4;
  bf16_t* base; float scale;
  if (row < NH * S) { base = Qb + (size_t)row * DH; scale = qscale; }
  else { base = Kb + (size_t)(row - NH * S) * DH; scale = 1.0f; }
  int p = row & (S - 1);
  bf16x4 lo = *(bf16x4*)(base + i);
  bf16x4 hi = *(bf16x4*)(base + i + 64);
  float4 t0 = *(const float4*)(tab + p * 64 + i);
  float4 t1 = *(const float4*)(tab + p * 64 + i + 2);
  float sv[4] = {t0.x, t0.z, t1.x, t1.z};
  float cv[4] = {t0.y, t0.w, t1.y, t1.w};
  bf16x4 nlo, nhi;
  #pragma unroll
  for (int j = 0; j < 4; ++j) {
    float a = (float)lo[j], b = (float)hi[j];
    nlo[j] = (bf16_t)((a * cv[j] - b * sv[j]) * scale);
    nhi[j] = (bf16_t)((b * cv[j] + a * sv[j]) * scale);
  }
  *(bf16x4*)(base + i) = nlo;
  *(bf16x4*)(base + i + 64) = nhi;
}

// ---- fused QKV projection GEMM (BM=128, BN=64, BK=64, 768 blocks)
__global__ __launch_bounds__(256)
void proj_gemm_k(const bf16_t* __restrict__ xq, const bf16_t* __restrict__ xk,
                 const bf16_t* __restrict__ xv, const bf16_t* __restrict__ wqT,
                 const bf16_t* __restrict__ wkT, const bf16_t* __restrict__ wvT,
                 const float* __restrict__ bQ, const float* __restrict__ bK,
                 const float* __restrict__ bV, bf16_t* __restrict__ Qb,
                 bf16_t* __restrict__ Kb, bf16_t* __restrict__ Vt) {
  const int nb = blockIdx.x;
  const int m0 = blockIdx.y * 128;
  const bf16_t* A; const bf16_t* B; const float* bias; bf16_t* dst; int ncol0;
  bool vmode = false;
  if (nb < 32)      { A = xq; B = wqT; bias = bQ; dst = Qb; ncol0 = nb * 64; }
  else if (nb < 40) { A = xk; B = wkT; bias = bK; dst = Kb; ncol0 = (nb - 32) * 64; }
  else              { A = xv; B = wvT; bias = bV; dst = Vt; ncol0 = (nb - 40) * 64; vmode = true; }
  const int K = 2048;
  const int t = threadIdx.x;
  const int lane = t & 63, w = t >> 6;
  const int l15 = lane & 15, lg = lane >> 4;
  const int wr = (w >> 1) * 64, wc = (w & 1) * 32;

  __shared__ bf16_t lA[2][128 * 64];
  __shared__ bf16_t lB[2][64 * 64];

  f32x4 acc[4][2] = {};
  const int srow = t >> 3;
  const int sslot = t & 7;

  auto stage = [&](int buf, int kt) {
    #pragma unroll
    for (int i = 0; i < 4; ++i) {
      int row = i * 32 + srow;
      int ss = sslot ^ (row & 7);
      gload_lds16(A + (size_t)(m0 + row) * K + kt * 64 + ss * 8,
                  (void*)(&lA[buf][0] + i * 2048 + t * 8));
    }
    #pragma unroll
    for (int i = 0; i < 2; ++i) {
      int row = i * 32 + srow;
      int ss = sslot ^ (row & 7);
      gload_lds16(B + (size_t)(ncol0 + row) * K + kt * 64 + ss * 8,
                  (void*)(&lB[buf][0] + i * 2048 + t * 8));
    }
  };

  const int nk = K >> 6;
  stage(0, 0);
  for (int kt = 0; kt < nk; ++kt) {
    const int cur = kt & 1;
    if (kt + 1 < nk) {
      stage(cur ^ 1, kt + 1);
      wait_vmcnt<6>();
    } else {
      wait_vmcnt<0>();
    }
    __builtin_amdgcn_s_barrier();
    #pragma unroll
    for (int kk = 0; kk < 2; ++kk) {
      bf16x8 af[4], bfv[2];
      #pragma unroll
      for (int f = 0; f < 4; ++f) {
        int row = wr + f * 16 + l15;
        int slot = kk * 4 + lg;
        af[f] = *(const bf16x8*)(&lA[cur][0] + row * 64 + ((slot ^ (row & 7)) * 8));
      }
      #pragma unroll
      for (int f = 0; f < 2; ++f) {
        int row = wc + f * 16 + l15;
        int slot = kk * 4 + lg;
        bfv[f] = *(const bf16x8*)(&lB[cur][0] + row * 64 + ((slot ^ (row & 7)) * 8));
      }
      #pragma unroll
      for (int fm = 0; fm < 4; ++fm)
        #pragma unroll
        for (int fn = 0; fn < 2; ++fn)
          acc[fm][fn] = MFMA16(af[fm], bfv[fn], acc[fm][fn]);
    }
    wait_lgkm0();
    __builtin_amdgcn_s_barrier();
  }

  #pragma unroll
  for (int fm = 0; fm < 4; ++fm) {
    int rowb = m0 + wr + fm * 16 + lg * 4;
    #pragma unroll
    for (int fn = 0; fn < 2; ++fn) {
      int col = ncol0 + wc + fn * 16 + l15;
      float bb = bias[col];
      if (vmode) {
        bf16x4 pk;
        #pragma unroll
        for (int r = 0; r < 4; ++r) pk[r] = (bf16_t)(acc[fm][fn][r] + bb);
        *(bf16x4*)(dst + (size_t)col * S + rowb) = pk;
      } else {
        #pragma unroll
        for (int r = 0; r < 4; ++r) {
          float v = acc[fm][fn][r] + bb;
          dst[((size_t)(col >> 7) * S + (rowb + r)) * DH + (col & 127)] = (bf16_t)v;
        }
      }
    }
  }
}

// ---- O-projection GEMM
__global__ __launch_bounds__(256)
void gemm_o_k(const bf16_t* __restrict__ A, const bf16_t* __restrict__ B,
              const float* __restrict__ bias, float* __restrict__ Cout) {
  const int ncol0 = blockIdx.x * 64;
  const int m0 = blockIdx.y * 128;
  const int K = 2048;
  const int t = threadIdx.x;
  const int lane = t & 63, w = t >> 6;
  const int l15 = lane & 15, lg = lane >> 4;
  const int wr = (w >> 1) * 64, wc = (w & 1) * 32;

  __shared__ bf16_t lA[2][128 * 64];
  __shared__ bf16_t lB[2][64 * 64];

  f32x4 acc[4][2] = {};
  const int srow = t >> 3;
  const int sslot = t & 7;

  auto stage = [&](int buf, int kt) {
    #pragma unroll
    for (int i = 0; i < 4; ++i) {
      int row = i * 32 + srow;
      int ss = sslot ^ (row & 7);
      gload_lds16(A + (size_t)(m0 + row) * K + kt * 64 + ss * 8,
                  (void*)(&lA[buf][0] + i * 2048 + t * 8));
    }
    #pragma unroll
    for (int i = 0; i < 2; ++i) {
      int row = i * 32 + srow;
      int ss = sslot ^ (row & 7);
      gload_lds16(B + (size_t)(ncol0 + row) * K + kt * 64 + ss * 8,
                  (void*)(&lB[buf][0] + i * 2048 + t * 8));
    }
  };

  const int nk = K >> 6;
  stage(0, 0);
  for (int kt = 0; kt < nk; ++kt) {
    const int cur = kt & 1;
    if (kt + 1 < nk) {
      stage(cur ^ 1, kt + 1);
      wait_vmcnt<6>();
    } else {
      wait_vmcnt<0>();
    }
    __builtin_amdgcn_s_barrier();
    #pragma unroll
    for (int kk = 0; kk < 2; ++kk) {
      bf16x8 af[4], bfv[2];
      #pragma unroll
      for (int f = 0; f < 4; ++f) {
        int row = wr + f * 16 + l15;
        int slot = kk * 4 + lg;
        af[f] = *(const bf16x8*)(&lA[cur][0] + row * 64 + ((slot ^ (row & 7)) * 8));
      }
      #pragma unroll
      for (int f = 0; f < 2; ++f) {
        int row = wc + f * 16 + l15;
        int slot = kk * 4 + lg;
        bfv[f] = *(const bf16x8*)(&lB[cur][0] + row * 64 + ((slot ^ (row & 7)) * 8));
      }
      #pragma unroll
      for (int fm = 0; fm < 4; ++fm)
        #pragma unroll
        for (int fn = 0; fn < 2; ++fn)
          acc[fm][fn] = MFMA16(af[fm], bfv[fn], acc[fm][fn]);
    }
    wait_lgkm0();
    __builtin_amdgcn_s_barrier();
  }

  #pragma unroll
  for (int fm = 0; fm < 4; ++fm) {
    int rowb = m0 + wr + fm * 16 + lg * 4;
    #pragma unroll
    for (int fn = 0; fn < 2; ++fn) {
      int col = ncol0 + wc + fn * 16 + l15;
      float bb = bias[col];
      #pragma unroll
      for (int r = 0; r < 4; ++r)
        Cout[(size_t)(rowb + r) * DM + col] = acc[fm][fn][r] + bb;
    }
  }
}

// ---- flash attention: QBLK=128/block, 4 waves x 32 q-rows, swapped QK^T (32x32),
// in-register softmax via cvt_pk + permlane32_swap, no P LDS. 384 blocks,
// qb>=8 split in two chunks (f32 partials + combine).
__global__ __launch_bounds__(256, 2)
void attn_k(const bf16_t* __restrict__ Q, const bf16_t* __restrict__ K,
            const bf16_t* __restrict__ Vt, bf16_t* __restrict__ Z,
            float* __restrict__ Opart, float* __restrict__ mpart,
            float* __restrict__ lpart) {
  const int bid = blockIdx.x;
  const int h = bid & 15;
  const int g = bid >> 4;
  const int code = attn_map[g];
  const int qb = code >> 1, ci = code & 1;
  const bool split = qb >= 8;
  const int kt0 = (split && ci) ? (qb + 1) : 0;
  const int ktend = split ? (ci ? 2 * qb + 1 : qb) : 2 * qb + 1;
  const int q0 = qb * 128;
  const int hkv = h >> 2;
  const int t = threadIdx.x;
  const int lane = t & 63, w = t >> 6;
  const int l31 = lane & 31, hi = lane >> 5;
  const int qrow = q0 + w * 32 + l31;

  __shared__ bf16_t lK[2][64 * 128];  // [key][d], 16 slots of 8, slot ^= row&15
  __shared__ bf16_t lV[2][128 * 64];  // [d][key], 8 slots of 8, slot ^= row&7

  bf16x8 qf[8];
  #pragma unroll
  for (int j = 0; j < 8; ++j)
    qf[j] = *(const bf16x8*)(Q + ((size_t)h * S + qrow) * DH + j * 16 + hi * 8);

  auto stageKV = [&](int buf, int kt) {
    #pragma unroll
    for (int i = 0; i < 4; ++i) {
      int row = i * 16 + (t >> 4);
      int ss = (t & 15) ^ (row & 15);
      gload_lds16(K + ((size_t)hkv * S + kt * 64 + row) * DH + ss * 8,
                  (void*)(&lK[buf][0] + i * 2048 + t * 8));
    }
    #pragma unroll
    for (int i = 0; i < 4; ++i) {
      int row = i * 32 + (t >> 3);
      int ss = (t & 7) ^ (row & 7);
      gload_lds16(Vt + ((size_t)hkv * DH + row) * S + kt * 64 + ss * 8,
                  (void*)(&lV[buf][0] + i * 2048 + t * 8));
    }
  };

  f32x16 oacc0 = {}, oacc1 = {}, oacc2 = {}, oacc3 = {};
  float m_run = -3.0e3f, l_run = 0.f;

  stageKV(0, kt0);
  for (int kt = kt0; kt <= ktend; ++kt) {
    const int cur = (kt - kt0) & 1;
    if (kt < ktend) {
      stageKV(cur ^ 1, kt + 1);
      wait_vmcnt<8>();
    } else {
      wait_vmcnt<0>();
    }
    __builtin_amdgcn_s_barrier();

    // S^T = K_tile(64x128) * Q^T: lane holds q=l31; keys (r&3)+8*(r>>2)+4*hi (+32 for s1)
    f32x16 s0 = {}, s1 = {};
    __builtin_amdgcn_s_setprio(1);
    #pragma unroll
    for (int j = 0; j < 8; ++j) {
      int sIdx = j * 2 + hi;
      int r0 = l31;
      bf16x8 k0 = *(const bf16x8*)(&lK[cur][0] + r0 * 128 + ((sIdx ^ (r0 & 15)) * 8));
      s0 = MFMA32(k0, qf[j], s0);
      int r1 = 32 + l31;
      bf16x8 k1 = *(const bf16x8*)(&lK[cur][0] + r1 * 128 + ((sIdx ^ (r1 & 15)) * 8));
      s1 = MFMA32(k1, qf[j], s1);
    }
    __builtin_amdgcn_s_setprio(0);

    if (kt >= 2 * qb) {  // diag tiles: causal mask
      #pragma unroll
      for (int r = 0; r < 16; ++r) {
        int krow = kt * 64 + (r & 3) + 8 * (r >> 2) + 4 * hi;
        if (krow > qrow) s0[r] = -1e30f;
        if (krow + 32 > qrow) s1[r] = -1e30f;
      }
    }

    // row max (own 32) then cross-half via permlane
    float mxa = s0[0], mxb = s0[1], mxc = s0[2], mxd = s0[3];
    #pragma unroll
    for (int r = 4; r < 16; r += 4) {
      mxa = fmaxf(mxa, s0[r]); mxb = fmaxf(mxb, s0[r + 1]);
      mxc = fmaxf(mxc, s0[r + 2]); mxd = fmaxf(mxd, s0[r + 3]);
    }
    #pragma unroll
    for (int r = 0; r < 16; r += 4) {
      mxa = fmaxf(mxa, s1[r]); mxb = fmaxf(mxb, s1[r + 1]);
      mxc = fmaxf(mxc, s1[r + 2]); mxd = fmaxf(mxd, s1[r + 3]);
    }
    float mfull = swapred_max(fmaxf(fmaxf(mxa, mxb), fmaxf(mxc, mxd)));

    float m_new, alpha;
    bool nore = __all(mfull - m_run <= 8.0f);  // defer-max
    if (nore) { m_new = m_run; alpha = 1.0f; }
    else { m_new = fmaxf(m_run, mfull); alpha = exp2f(m_run - m_new); }

    float psa = 0.f, psb = 0.f, psc = 0.f, psd = 0.f;
    #pragma unroll
    for (int r = 0; r < 16; r += 4) {
      s0[r] = exp2f(s0[r] - m_new); psa += s0[r];
      s0[r + 1] = exp2f(s0[r + 1] - m_new); psb += s0[r + 1];
      s0[r + 2] = exp2f(s0[r + 2] - m_new); psc += s0[r + 2];
      s0[r + 3] = exp2f(s0[r + 3] - m_new); psd += s0[r + 3];
    }
    #pragma unroll
    for (int r = 0; r < 16; r += 4) {
      s1[r] = exp2f(s1[r] - m_new); psa += s1[r];
      s1[r + 1] = exp2f(s1[r + 1] - m_new); psb += s1[r + 1];
      s1[r + 2] = exp2f(s1[r + 2] - m_new); psc += s1[r + 2];
      s1[r + 3] = exp2f(s1[r + 3] - m_new); psd += s1[r + 3];
    }
    float lt = swapred_sum((psa + psb) + (psc + psd));
    l_run = l_run * alpha + lt;
    m_run = m_new;

    if (!nore) {
      #pragma unroll
      for (int r = 0; r < 16; ++r) {
        int qs = (r & 3) + 8 * (r >> 2) + 4 * hi;
        float ar = __shfl(alpha, qs);
        oacc0[r] *= ar; oacc1[r] *= ar; oacc2[r] *= ar; oacc3[r] *= ar;
      }
    }

    // PV A-fragments fully in registers
    bf16x8 pa[4];
    pa[0] = packfrag(s0[0], s0[1], s0[2], s0[3], s0[4], s0[5], s0[6], s0[7]);
    pa[1] = packfrag(s0[8], s0[9], s0[10], s0[11], s0[12], s0[13], s0[14], s0[15]);
    pa[2] = packfrag(s1[0], s1[1], s1[2], s1[3], s1[4], s1[5], s1[6], s1[7]);
    pa[3] = packfrag(s1[8], s1[9], s1[10], s1[11], s1[12], s1[13], s1[14], s1[15]);

    __builtin_amdgcn_s_setprio(1);
#define PVBLK(OA, db) { \
    int dr = (db) * 32 + l31; \
    _Pragma("unroll") \
    for (int ks = 0; ks < 4; ++ks) { \
      int sIdx = ks * 2 + hi; \
      bf16x8 vf = *(const bf16x8*)(&lV[cur][0] + dr * 64 + ((sIdx ^ (dr & 7)) * 8)); \
      OA = MFMA32(pa[ks], vf, OA); \
    } }
    PVBLK(oacc0, 0)
    PVBLK(oacc1, 1)
    PVBLK(oacc2, 2)
    PVBLK(oacc3, 3)
#undef PVBLK
    __builtin_amdgcn_s_setprio(0);
    wait_lgkm0();
    __builtin_amdgcn_s_barrier();
  }

  if (!split) {
    float linv = 1.0f / l_run;
    #pragma unroll
    for (int r = 0; r < 16; ++r) {
      int qs = (r & 3) + 8 * (r >> 2) + 4 * hi;
      float lv = __shfl(linv, qs);
      int qg = q0 + w * 32 + qs;
      bf16_t* zp = Z + (size_t)qg * DM + h * DH + l31;
      zp[0]  = (bf16_t)(oacc0[r] * lv);
      zp[32] = (bf16_t)(oacc1[r] * lv);
      zp[64] = (bf16_t)(oacc2[r] * lv);
      zp[96] = (bf16_t)(oacc3[r] * lv);
    }
  } else {
    const int slot = (h * 8 + (qb - 8)) * 2 + ci;
    float* Op = Opart + (size_t)slot * 16384;
    #pragma unroll
    for (int r = 0; r < 16; ++r) {
      int qs = (r & 3) + 8 * (r >> 2) + 4 * hi;
      float* op = Op + (w * 32 + qs) * 128 + l31;
      op[0] = oacc0[r]; op[32] = oacc1[r]; op[64] = oacc2[r]; op[96] = oacc3[r];
    }
    if (lane < 32) {
      mpart[slot * 128 + w * 32 + l31] = m_run;
      lpart[slot * 128 + w * 32 + l31] = l_run;
    }
  }
}

// ---- combine: merge the 2 chunks of each qb>=8 unit
__global__ void combine_k(const float* __restrict__ Opart, const float* __restrict__ mpart,
                          const float* __restrict__ lpart, bf16_t* __restrict__ Z) {
  int tid = blockIdx.x * 256 + threadIdx.x;  // 2^21
  int d = tid & 127;
  int q = (tid >> 7) & 127;
  int qb8 = (tid >> 14) & 7;
  int h = tid >> 17;
  int s0 = (h * 8 + qb8) * 2;
  float m0 = mpart[s0 * 128 + q], m1 = mpart[(s0 + 1) * 128 + q];
  float l0 = lpart[s0 * 128 + q], l1 = lpart[(s0 + 1) * 128 + q];
  float M = fmaxf(m0, m1);
  float a0 = exp2f(m0 - M), a1 = exp2f(m1 - M);
  float L = a0 * l0 + a1 * l1;
  float o0 = Opart[(size_t)s0 * 16384 + q * 128 + d];
  float o1 = Opart[(size_t)(s0 + 1) * 16384 + q * 128 + d];
  int qg = (8 + qb8) * 128 + q;
  Z[(size_t)qg * DM + h * DH + d] = (bf16_t)((a0 * o0 + a1 * o1) / L);
}

extern "C" void kernel_launch(void* const* d_in, const int* in_sizes, int n_in,
                              void* d_out, int out_size, void* d_ws, size_t ws_size,
                              hipStream_t stream) {
  (void)in_sizes; (void)n_in; (void)out_size; (void)ws_size;
  const float* Xq = (const float*)d_in[0];
  const float* Xk = (const float*)d_in[1];
  const float* Xv = (const float*)d_in[2];
  const float* WQ = (const float*)d_in[3];
  const float* bQ = (const float*)d_in[4];
  const float* WK = (const float*)d_in[5];
  const float* bK = (const float*)d_in[6];
  const float* WV = (const float*)d_in[7];
  const float* bV = (const float*)d_in[8];
  const float* WO = (const float*)d_in[9];
  const float* bO = (const float*)d_in[10];

  char* w = (char*)d_ws;
  float2* tab = (float2*)w;                // 1 MiB
  bf16_t* xq  = (bf16_t*)(w + (1 << 20));  // 8 MiB
  bf16_t* xk  = xq + 4194304;              // 8 MiB
  bf16_t* xv  = xk + 4194304;              // 8 MiB
  bf16_t* wqT = xv + 4194304;              // 8 MiB
  bf16_t* wkT = wqT + 4194304;             // 2 MiB
  bf16_t* wvT = wkT + 1048576;             // 2 MiB
  bf16_t* woT = wvT + 1048576;             // 8 MiB
  bf16_t* Qb  = woT + 4194304;             // 8 MiB
  bf16_t* Kb  = Qb + 4194304;              // 2 MiB
  bf16_t* Vtb = Kb + 1048576;              // 2 MiB  [4][128][2048]
  bf16_t* Zb  = Vtb + 1048576;             // 8 MiB
  // attn partials overlay xq/xk (dead after proj): 16 MiB; m/l overlay xv
  float* Opart = (float*)xq;               // 256 slots * 16384 f32
  float* mpart = (float*)xv;               // 256 * 128 f32
  float* lpart = mpart + 256 * 128;

  rope_table_k<<<dim3(S), dim3(64), 0, stream>>>(tab);
  cvt3_k<<<dim3(12288), dim3(256), 0, stream>>>(Xq, Xk, Xv, xq, xk, xv);
  transpose_w_k<<<dim3(4, 64, 16), dim3(32, 8), 0, stream>>>(WQ, wqT, 2048, 128, 128, 0, 2048);
  transpose_wkv_k<<<dim3(4, 64, 8), dim3(32, 8), 0, stream>>>(WK, WV, wkT, wvT);
  transpose_w_k<<<dim3(64, 4, 16), dim3(32, 8), 0, stream>>>(WO, woT, 128, 2048, 0, 128, 2048);

  proj_gemm_k<<<dim3(48, 16), dim3(256), 0, stream>>>(xq, xk, xv, wqT, wkT, wvT,
                                                      bQ, bK, bV, Qb, Kb, Vtb);

  const float qscale = 1.4426950408889634f / sqrtf(128.0f);  // log2e / sqrt(D_HEAD)
  rope_qk_k<<<dim3(2560), dim3(256), 0, stream>>>(Qb, Kb, tab, qscale);

  attn_k<<<dim3(384), dim3(256), 0, stream>>>(Qb, Kb, Vtb, Zb, Opart, mpart, lpart);
  combine_k<<<dim3(8192), dim3(256), 0, stream>>>(Opart, mpart, lpart, Zb);

  gemm_o_k<<<dim3(32, 16), dim3(256), 0, stream>>>(Zb, woT, bO, (float*)d_out);
}